// Round 4
// baseline (893.154 us; speedup 1.0000x reference)
//
#include <hip/hip_runtime.h>
#include <math.h>

#define TAUF 0.9f

typedef unsigned int u32;
typedef unsigned short ushort;
typedef __attribute__((ext_vector_type(8))) short short8;
typedef __attribute__((ext_vector_type(4))) float f32x4;
typedef __attribute__((ext_vector_type(4))) unsigned short us4;

__device__ __forceinline__ float wave_sum(float v) {
#pragma unroll
  for (int off = 32; off > 0; off >>= 1) v += __shfl_down(v, off, 64);
  return __shfl(v, 0, 64);
}

__device__ __forceinline__ ushort f2bf(float f) {
  u32 u = __builtin_bit_cast(u32, f);
  u32 r = (u + 0x7FFFu + ((u >> 16) & 1u)) >> 16;
  return (ushort)r;
}
__device__ __forceinline__ float bf2f(ushort s) {
  u32 u = ((u32)s) << 16;
  return __builtin_bit_cast(float, u);
}

__device__ __forceinline__ void gload16(const void* g, void* l) {
  __builtin_amdgcn_global_load_lds(
      (const __attribute__((address_space(1))) u32*)g,
      (__attribute__((address_space(3))) u32*)l, 16, 0, 0);
}

// ---------------- f32 input GEMM: h = relu(X @ Wi + bi) ----------------------
// BM=64, BN=256 (full width), BK=16, 256 threads, 8x8 microtile (cols split as
// tx*4 and 128+tx*4 so LDS float4 reads are contiguous = minimal bank cost).
// Epilogue: writes h (f32), hn = LN1_layer0(h) (bf16), and exact f32 row stats
// delta/adst/asrc/xwp (direct stores - each block owns full rows).
__launch_bounds__(256)
__global__ void gemm_in(const float* __restrict__ A, const float* __restrict__ B,
                        const float* __restrict__ bias, const float* __restrict__ Wa,
                        const float* __restrict__ wp, const float* __restrict__ g1,
                        const float* __restrict__ b1g, float* __restrict__ C,
                        ushort* __restrict__ hn, float* __restrict__ delta,
                        float* __restrict__ adst, float* __restrict__ asrc,
                        float* __restrict__ xwp, int M, int K) {
  __shared__ float As[16][68];    // [k][m], padded
  __shared__ float Bs[16 * 256];  // [k][n], flat contiguous staging
  const int tid = threadIdx.x;
  const int tx = tid & 31, ty = tid >> 5;
  const int bm = blockIdx.x * 64;
  float acc[8][8] = {};
  const int aRow = tid >> 2, aC4 = (tid & 3) << 2;
  for (int k0 = 0; k0 < K; k0 += 16) {
    int ar = bm + aRow; ar = (ar < M) ? ar : (M - 1);
    float4 av = *reinterpret_cast<const float4*>(A + (size_t)ar * K + k0 + aC4);
    As[aC4 + 0][aRow] = av.x;
    As[aC4 + 1][aRow] = av.y;
    As[aC4 + 2][aRow] = av.z;
    As[aC4 + 3][aRow] = av.w;
#pragma unroll
    for (int t = 0; t < 4; ++t) {
      int ft = t * 256 + tid;                 // float4 index in 16x256 tile
      int row = ft >> 6, col = (ft & 63) * 4;
      *reinterpret_cast<float4*>(&Bs[ft * 4]) =
          *reinterpret_cast<const float4*>(B + (size_t)(k0 + row) * 256 + col);
    }
    __syncthreads();
#pragma unroll
    for (int k = 0; k < 16; ++k) {
      float4 a0 = *reinterpret_cast<const float4*>(&As[k][ty * 8]);
      float4 a1 = *reinterpret_cast<const float4*>(&As[k][ty * 8 + 4]);
      float4 b0 = *reinterpret_cast<const float4*>(&Bs[k * 256 + tx * 4]);
      float4 b1 = *reinterpret_cast<const float4*>(&Bs[k * 256 + 128 + tx * 4]);
      float ar8[8] = {a0.x, a0.y, a0.z, a0.w, a1.x, a1.y, a1.z, a1.w};
      float br8[8] = {b0.x, b0.y, b0.z, b0.w, b1.x, b1.y, b1.z, b1.w};
#pragma unroll
      for (int i = 0; i < 8; ++i)
#pragma unroll
        for (int j = 0; j < 8; ++j) acc[i][j] += ar8[i] * br8[j];
    }
    __syncthreads();
  }
  // per-column constants for this thread's 8 cols: tx*4+{0..3}, 128+tx*4+{0..3}
  float bb[8], wa0[8], wa1[8], wpv[8], gg[8], gb[8];
#pragma unroll
  for (int t = 0; t < 2; ++t) {
    int c = tx * 4 + t * 128;
    float4 b4 = *reinterpret_cast<const float4*>(bias + c);
    float4 w0 = *reinterpret_cast<const float4*>(Wa + c);
    float4 w1 = *reinterpret_cast<const float4*>(Wa + 256 + c);
    float4 wv = *reinterpret_cast<const float4*>(wp + c);
    float4 g4 = *reinterpret_cast<const float4*>(g1 + c);
    float4 h4 = *reinterpret_cast<const float4*>(b1g + c);
    bb[t*4+0]=b4.x; bb[t*4+1]=b4.y; bb[t*4+2]=b4.z; bb[t*4+3]=b4.w;
    wa0[t*4+0]=w0.x; wa0[t*4+1]=w0.y; wa0[t*4+2]=w0.z; wa0[t*4+3]=w0.w;
    wa1[t*4+0]=w1.x; wa1[t*4+1]=w1.y; wa1[t*4+2]=w1.z; wa1[t*4+3]=w1.w;
    wpv[t*4+0]=wv.x; wpv[t*4+1]=wv.y; wpv[t*4+2]=wv.z; wpv[t*4+3]=wv.w;
    gg[t*4+0]=g4.x; gg[t*4+1]=g4.y; gg[t*4+2]=g4.z; gg[t*4+3]=g4.w;
    gb[t*4+0]=h4.x; gb[t*4+1]=h4.y; gb[t*4+2]=h4.z; gb[t*4+3]=h4.w;
  }
#pragma unroll
  for (int i = 0; i < 8; ++i) {
    const int row = bm + ty * 8 + i;
    float v[8];
    float p0 = 0.f, p1 = 0.f, p2 = 0.f, p3 = 0.f, p4 = 0.f;
#pragma unroll
    for (int j = 0; j < 8; ++j) {
      float t = acc[i][j] + bb[j];
      t = fmaxf(t, 0.f);
      v[j] = t;
      p0 += t;                 // sum x (= sum|x| post-relu; also LN mean numer)
      p1 += t * wa0[j];
      p2 += t * wa1[j];
      p3 += t * wpv[j];
      p4 += t * t;             // LN sumsq
    }
#pragma unroll
    for (int off = 16; off > 0; off >>= 1) {
      p0 += __shfl_xor(p0, off, 64);
      p1 += __shfl_xor(p1, off, 64);
      p2 += __shfl_xor(p2, off, 64);
      p3 += __shfl_xor(p3, off, 64);
      p4 += __shfl_xor(p4, off, 64);
    }
    if (row < M) {
      if (tx == 0) {
        delta[row] = p0; adst[row] = p1; asrc[row] = p2; xwp[row] = p3;
      }
      *reinterpret_cast<float4*>(C + (size_t)row * 256 + tx * 4) =
          make_float4(v[0], v[1], v[2], v[3]);
      *reinterpret_cast<float4*>(C + (size_t)row * 256 + 128 + tx * 4) =
          make_float4(v[4], v[5], v[6], v[7]);
      float mu = p0 * (1.f / 256.f);
      float var = p4 * (1.f / 256.f) - mu * mu;
      float is = rsqrtf(var + 1e-5f);
      us4 o0, o1;
      o0.x = f2bf((v[0]-mu)*is*gg[0]+gb[0]); o0.y = f2bf((v[1]-mu)*is*gg[1]+gb[1]);
      o0.z = f2bf((v[2]-mu)*is*gg[2]+gb[2]); o0.w = f2bf((v[3]-mu)*is*gg[3]+gb[3]);
      o1.x = f2bf((v[4]-mu)*is*gg[4]+gb[4]); o1.y = f2bf((v[5]-mu)*is*gg[5]+gb[5]);
      o1.z = f2bf((v[6]-mu)*is*gg[6]+gb[6]); o1.w = f2bf((v[7]-mu)*is*gg[7]+gb[7]);
      *reinterpret_cast<us4*>(hn + (size_t)row * 256 + tx * 4) = o0;
      *reinterpret_cast<us4*>(hn + (size_t)row * 256 + 128 + tx * 4) = o1;
    }
  }
}

// ---------------- bf16 MFMA GEMM: C = epi(A @ Bt^T + bias) -------------------
// EPI: 1 bias->bf16, 2 bias+gelu->bf16.  BM=BN=128, BK=64, 4 waves.
template <int EPI>
__launch_bounds__(256)
__global__ void gemm_mfma(const ushort* __restrict__ A, const ushort* __restrict__ Bt,
                          const float* __restrict__ bias, ushort* __restrict__ Cb,
                          int M, int N, int K) {
  __shared__ ushort As[128 * 64];
  __shared__ ushort Bs[128 * 64];
  const int tid = threadIdx.x;
  const int wave = tid >> 6, lane = tid & 63;
  const int bm = blockIdx.x * 128, bn = blockIdx.y * 128;
  const int wm = (wave >> 1) * 64, wn = (wave & 1) * 64;
  const int srow = lane >> 3;
  const int scol = (((lane & 7) ^ srow) << 3);

  f32x4 acc[4][4];
#pragma unroll
  for (int i = 0; i < 4; ++i)
#pragma unroll
    for (int j = 0; j < 4; ++j) acc[i][j] = (f32x4){0.f, 0.f, 0.f, 0.f};

  for (int k0 = 0; k0 < K; k0 += 64) {
#pragma unroll
    for (int r = 0; r < 4; ++r) {
      const int ch = r * 4 + wave;
      int ar = bm + ch * 8 + srow;
      ar = (ar < M) ? ar : (M - 1);
      gload16(A + (size_t)ar * K + k0 + scol, (char*)As + ch * 1024);
      const int br = bn + ch * 8 + srow;
      gload16(Bt + (size_t)br * K + k0 + scol, (char*)Bs + ch * 1024);
    }
    __syncthreads();
#pragma unroll
    for (int kk = 0; kk < 2; ++kk) {
      const int c = (kk * 32 + (lane >> 4) * 8) * 2;
      short8 a[4];
#pragma unroll
      for (int mi = 0; mi < 4; ++mi) {
        const int rr = wm + mi * 16 + (lane & 15);
        a[mi] = *(const short8*)((const char*)As + rr * 128 + (c ^ ((rr & 7) << 4)));
      }
#pragma unroll
      for (int ni = 0; ni < 4; ++ni) {
        const int rr = wn + ni * 16 + (lane & 15);
        short8 b = *(const short8*)((const char*)Bs + rr * 128 + (c ^ ((rr & 7) << 4)));
#pragma unroll
        for (int mi = 0; mi < 4; ++mi)
          acc[mi][ni] = __builtin_amdgcn_mfma_f32_16x16x32_bf16(a[mi], b,
                                                                acc[mi][ni], 0, 0, 0);
      }
    }
    __syncthreads();
  }

  float bb[4];
#pragma unroll
  for (int ni = 0; ni < 4; ++ni) bb[ni] = bias[bn + wn + ni * 16 + (lane & 15)];
#pragma unroll
  for (int mi = 0; mi < 4; ++mi) {
#pragma unroll
    for (int reg = 0; reg < 4; ++reg) {
      const int row = bm + wm + mi * 16 + (lane >> 4) * 4 + reg;
      if (row >= M) continue;
#pragma unroll
      for (int ni = 0; ni < 4; ++ni) {
        const int col = bn + wn + ni * 16 + (lane & 15);
        float v = acc[mi][ni][reg] + bb[ni];
        if (EPI == 2) v = v * 0.5f * (1.f + erff(v * 0.70710678118654752f));
        Cb[(size_t)row * N + col] = f2bf(v);
      }
    }
  }
}

// ---------------- FFN2 GEMM, full-width: h' = h + (u @ W2t^T + b2) -----------
// BM=128, BN=256(=full), BK=64, K=512, 4 waves (2x2, each 64 rows x 128 cols).
// LAST=0: store h'; hn = LN1_{l+1}(h') (cross-wave LDS reduce).
// LAST=1: hn = bf16(h') only (feeds output projection); h not stored.
template <int LAST>
__launch_bounds__(256)
__global__ void gemm_ffn2(const ushort* __restrict__ A, const ushort* __restrict__ Bt,
                          const float* __restrict__ bias, const float* __restrict__ g1,
                          const float* __restrict__ b1g, float* __restrict__ h,
                          ushort* __restrict__ hn, int M) {
  __shared__ ushort As[128 * 64];
  __shared__ ushort Bs[256 * 64];
  __shared__ float lnS[2][128], lnQ[2][128];
  const int tid = threadIdx.x;
  const int wave = tid >> 6, lane = tid & 63;
  const int bm = blockIdx.x * 128;
  const int wm = (wave >> 1) * 64, wn = (wave & 1) * 128;
  const int srow = lane >> 3;
  const int scol = (((lane & 7) ^ srow) << 3);

  f32x4 acc[4][8];
#pragma unroll
  for (int i = 0; i < 4; ++i)
#pragma unroll
    for (int j = 0; j < 8; ++j) acc[i][j] = (f32x4){0.f, 0.f, 0.f, 0.f};

  for (int k0 = 0; k0 < 512; k0 += 64) {
#pragma unroll
    for (int r = 0; r < 4; ++r) {
      const int ch = r * 4 + wave;
      int ar = bm + ch * 8 + srow;
      ar = (ar < M) ? ar : (M - 1);
      gload16(A + (size_t)ar * 512 + k0 + scol, (char*)As + ch * 1024);
    }
#pragma unroll
    for (int r = 0; r < 8; ++r) {
      const int ch = r * 4 + wave;
      const int br = ch * 8 + srow;
      gload16(Bt + (size_t)br * 512 + k0 + scol, (char*)Bs + ch * 1024);
    }
    __syncthreads();
#pragma unroll
    for (int kk = 0; kk < 2; ++kk) {
      const int c = (kk * 32 + (lane >> 4) * 8) * 2;
      short8 a[4];
#pragma unroll
      for (int mi = 0; mi < 4; ++mi) {
        const int rr = wm + mi * 16 + (lane & 15);
        a[mi] = *(const short8*)((const char*)As + rr * 128 + (c ^ ((rr & 7) << 4)));
      }
#pragma unroll
      for (int ni = 0; ni < 8; ++ni) {
        const int rr = wn + ni * 16 + (lane & 15);
        short8 b = *(const short8*)((const char*)Bs + rr * 128 + (c ^ ((rr & 7) << 4)));
#pragma unroll
        for (int mi = 0; mi < 4; ++mi)
          acc[mi][ni] = __builtin_amdgcn_mfma_f32_16x16x32_bf16(a[mi], b,
                                                                acc[mi][ni], 0, 0, 0);
      }
    }
    __syncthreads();
  }

  float bb[8];
#pragma unroll
  for (int ni = 0; ni < 8; ++ni) bb[ni] = bias[wn + ni * 16 + (lane & 15)];

  // pass 1: t = h + v; store (h or bf16); LN partials -> LDS
#pragma unroll
  for (int mi = 0; mi < 4; ++mi) {
#pragma unroll
    for (int reg = 0; reg < 4; ++reg) {
      const int lrow = wm + mi * 16 + (lane >> 4) * 4 + reg;
      const int row = bm + lrow;
      const bool ok = (row < M);
      float pS = 0.f, pQ = 0.f;
#pragma unroll
      for (int ni = 0; ni < 8; ++ni) {
        const int col = wn + ni * 16 + (lane & 15);
        float t = acc[mi][ni][reg] + bb[ni] + h[(size_t)row * 256 + col];
        acc[mi][ni][reg] = t;
        if (LAST) {
          if (ok) hn[(size_t)row * 256 + col] = f2bf(t);
        } else {
          if (ok) h[(size_t)row * 256 + col] = t;
          pS += t;
          pQ += t * t;
        }
      }
      if (!LAST) {
#pragma unroll
        for (int off = 8; off > 0; off >>= 1) {
          pS += __shfl_xor(pS, off, 16);
          pQ += __shfl_xor(pQ, off, 16);
        }
        if ((lane & 15) == 0) {
          lnS[wn >> 7][lrow] = pS;
          lnQ[wn >> 7][lrow] = pQ;
        }
      }
    }
  }
  if (LAST) return;
  __syncthreads();
  // pass 2: LN normalize with full-row stats
  float gg[8], gb[8];
#pragma unroll
  for (int ni = 0; ni < 8; ++ni) {
    gg[ni] = g1[wn + ni * 16 + (lane & 15)];
    gb[ni] = b1g[wn + ni * 16 + (lane & 15)];
  }
#pragma unroll
  for (int mi = 0; mi < 4; ++mi) {
#pragma unroll
    for (int reg = 0; reg < 4; ++reg) {
      const int lrow = wm + mi * 16 + (lane >> 4) * 4 + reg;
      const int row = bm + lrow;
      if (row >= M) continue;
      float S = lnS[0][lrow] + lnS[1][lrow];
      float Q = lnQ[0][lrow] + lnQ[1][lrow];
      float mu = S * (1.f / 256.f);
      float is = rsqrtf(Q * (1.f / 256.f) - mu * mu + 1e-5f);
#pragma unroll
      for (int ni = 0; ni < 8; ++ni) {
        const int col = wn + ni * 16 + (lane & 15);
        float t = acc[mi][ni][reg];
        hn[(size_t)row * 256 + col] = f2bf((t - mu) * is * gg[ni] + gb[ni]);
      }
    }
  }
}

// ---------------- bf16 MFMA output GEMM: C(f32) = A @ Bt^T + bias ------------
__launch_bounds__(256)
__global__ void gemm_out(const ushort* __restrict__ A, const ushort* __restrict__ Bt,
                         const float* __restrict__ bias, float* __restrict__ C, int M) {
  __shared__ ushort As[128 * 64];
  __shared__ ushort Bs[64 * 64];
  const int tid = threadIdx.x;
  const int wave = tid >> 6, lane = tid & 63;
  const int bm = blockIdx.x * 128;
  const int wm = wave * 32;
  const int srow = lane >> 3;
  const int scol = (((lane & 7) ^ srow) << 3);
  f32x4 acc[2][4];
#pragma unroll
  for (int i = 0; i < 2; ++i)
#pragma unroll
    for (int j = 0; j < 4; ++j) acc[i][j] = (f32x4){0.f, 0.f, 0.f, 0.f};

  for (int k0 = 0; k0 < 256; k0 += 64) {
#pragma unroll
    for (int r = 0; r < 4; ++r) {
      const int ch = r * 4 + wave;
      int ar = bm + ch * 8 + srow;
      ar = (ar < M) ? ar : (M - 1);
      gload16(A + (size_t)ar * 256 + k0 + scol, (char*)As + ch * 1024);
    }
#pragma unroll
    for (int r = 0; r < 2; ++r) {
      const int ch = r * 4 + wave;
      const int br = ch * 8 + srow;
      gload16(Bt + (size_t)br * 256 + k0 + scol, (char*)Bs + ch * 1024);
    }
    __syncthreads();
#pragma unroll
    for (int kk = 0; kk < 2; ++kk) {
      const int c = (kk * 32 + (lane >> 4) * 8) * 2;
      short8 a[2], b[4];
#pragma unroll
      for (int mi = 0; mi < 2; ++mi) {
        const int rr = wm + mi * 16 + (lane & 15);
        a[mi] = *(const short8*)((const char*)As + rr * 128 + (c ^ ((rr & 7) << 4)));
      }
#pragma unroll
      for (int ni = 0; ni < 4; ++ni) {
        const int rr = ni * 16 + (lane & 15);
        b[ni] = *(const short8*)((const char*)Bs + rr * 128 + (c ^ ((rr & 7) << 4)));
      }
#pragma unroll
      for (int mi = 0; mi < 2; ++mi)
#pragma unroll
        for (int ni = 0; ni < 4; ++ni)
          acc[mi][ni] = __builtin_amdgcn_mfma_f32_16x16x32_bf16(a[mi], b[ni],
                                                                acc[mi][ni], 0, 0, 0);
    }
    __syncthreads();
  }
  float bb[4];
#pragma unroll
  for (int ni = 0; ni < 4; ++ni) bb[ni] = bias[ni * 16 + (lane & 15)];
#pragma unroll
  for (int mi = 0; mi < 2; ++mi) {
#pragma unroll
    for (int reg = 0; reg < 4; ++reg) {
      const int row = bm + wm + mi * 16 + (lane >> 4) * 4 + reg;
      if (row >= M) continue;
#pragma unroll
      for (int ni = 0; ni < 4; ++ni) {
        const int col = ni * 16 + (lane & 15);
        C[(size_t)row * 64 + col] = acc[mi][ni][reg] + bb[ni];
      }
    }
  }
}

// ---- one-shot prep: all weight transposes+bf16 converts, plus zeroing -------
#define W_TOTAL (196608 + 393216 + 393216 + 16384)
__global__ void prep_k(const float* __restrict__ Wc, const float* __restrict__ W1,
                       const float* __restrict__ W2, const float* __restrict__ Wo,
                       ushort* __restrict__ WcT, ushort* __restrict__ W1T,
                       ushort* __restrict__ W2T, ushort* __restrict__ WoT,
                       float* __restrict__ zbase, int zn) {
  int i = blockIdx.x * 256 + threadIdx.x;
  if (i < W_TOTAL) {
    int j = i;
    if (j < 196608) {
      int l = j / 65536, r = j % 65536, n = r >> 8, k = r & 255;
      WcT[j] = f2bf(Wc[(size_t)l * 65536 + k * 256 + n]);
    } else if ((j -= 196608) < 393216) {
      int l = j / 131072, r = j % 131072, n = r >> 8, k = r & 255;
      W1T[j] = f2bf(W1[(size_t)l * 131072 + k * 512 + n]);
    } else if ((j -= 393216) < 393216) {
      int l = j / 131072, r = j % 131072, n = r >> 9, k = r & 511;
      W2T[j] = f2bf(W2[(size_t)l * 131072 + k * 256 + n]);
    } else {
      j -= 393216;
      int n = j >> 8, k = j & 255;
      WoT[j] = f2bf(Wo[k * 64 + n]);
    }
  } else {
    int z = i - W_TOTAL;
    if (z < zn) zbase[z] = 0.f;
  }
}

__global__ void neigh_k(const int* __restrict__ src, const int* __restrict__ dst,
                        const float* __restrict__ delta, float* __restrict__ neigh, int E) {
  int e = blockIdx.x * 256 + threadIdx.x;
  if (e < E) atomicAdd(&neigh[dst[e]], delta[src[e]]);
}

// edge logits (pi computed inline); slots layout [t][N]
__global__ void logits_k(const int* __restrict__ src, const int* __restrict__ dst,
                         const float* __restrict__ adst, const float* __restrict__ asrc,
                         const float* __restrict__ xwp, const float* __restrict__ neigh,
                         const float* __restrict__ Wa, const float* __restrict__ ba,
                         float* __restrict__ expe, float* __restrict__ denom,
                         int* __restrict__ cnt, int* __restrict__ slots,
                         int E, int Et, int N) {
  int e = blockIdx.x * 256 + threadIdx.x;
  if (e >= Et) return;
  int s, d;
  if (e < E) { s = src[e]; d = dst[e]; } else { s = e - E; d = s; }
  float pis = 1.f / (1.f + expf(-(xwp[s] + neigh[s])));
  float v = adst[d] + asrc[s] + pis * Wa[512] + ba[0];
  v = (v >= 0.f ? v : 0.2f * v) / TAUF;
  v = fminf(fmaxf(v, -5.f), 5.f);
  float ex = expf(v);
  expe[e] = ex;
  atomicAdd(&denom[d], ex);
  int p = atomicAdd(&cnt[d], 1);
  if (p < 64) slots[(size_t)p * N + d] = e;
}

__device__ __forceinline__ bool better(float a, int e, float a2, int e2) {
  return a > a2 || (a == a2 && e < e2);
}

__global__ void topk_k(const int* __restrict__ cnt, const int* __restrict__ slots,
                       const float* __restrict__ expe, const float* __restrict__ denom,
                       const int* __restrict__ src, int* __restrict__ kcnt,
                       int* __restrict__ ksrc, float* __restrict__ kw, int N, int E) {
  int d = blockIdx.x * 256 + threadIdx.x;
  if (d >= N) return;
  int deg = min(cnt[d], 64);
  float D = denom[d] + 1e-16f;
  float av[8]; int ai[8]; int kc = 0;
  for (int t = 0; t < deg; ++t) {
    int e = slots[(size_t)t * N + d];
    float a = expe[e] / D;
    if (kc < 8) {
      int p = kc++;
      while (p > 0 && better(a, e, av[p - 1], ai[p - 1])) {
        av[p] = av[p - 1]; ai[p] = ai[p - 1]; --p;
      }
      av[p] = a; ai[p] = e;
    } else if (better(a, e, av[7], ai[7])) {
      int p = 7;
      while (p > 0 && better(a, e, av[p - 1], ai[p - 1])) {
        av[p] = av[p - 1]; ai[p] = ai[p - 1]; --p;
      }
      av[p] = a; ai[p] = e;
    }
  }
  float ks = 0.f;
  for (int j = 0; j < kc; ++j) ks += av[j];
  kcnt[d] = kc;
  for (int j = 0; j < kc; ++j) {
    int e = ai[j];
    ksrc[(size_t)d * 8 + j] = (e < E) ? src[e] : (e - E);
    kw[(size_t)d * 8 + j] = av[j] / (ks + 1e-16f);
  }
}

// fused: h += relu(sum_j kw*xp[ksrc]); then LN2 -> hn (bf16). One wave per row.
__global__ void agg_ln_k(const ushort* __restrict__ xp, const int* __restrict__ kcnt,
                         const int* __restrict__ ksrc, const float* __restrict__ kw,
                         const float* __restrict__ g, const float* __restrict__ b,
                         float* __restrict__ h, ushort* __restrict__ hn, int N) {
  int d = blockIdx.x * 4 + (threadIdx.x >> 6);
  if (d >= N) return;
  int lane = threadIdx.x & 63;
  int kc = kcnt[d];
  float a0 = 0.f, a1 = 0.f, a2 = 0.f, a3 = 0.f;
  for (int j = 0; j < kc; ++j) {
    int s = ksrc[(size_t)d * 8 + j];
    float w = kw[(size_t)d * 8 + j];
    us4 xv = *reinterpret_cast<const us4*>(xp + (size_t)s * 256 + lane * 4);
    a0 += w * bf2f(xv.x);
    a1 += w * bf2f(xv.y);
    a2 += w * bf2f(xv.z);
    a3 += w * bf2f(xv.w);
  }
  float* hr = h + (size_t)d * 256 + lane * 4;
  float4 hv = *reinterpret_cast<const float4*>(hr);
  float v0 = hv.x + fmaxf(a0, 0.f);
  float v1 = hv.y + fmaxf(a1, 0.f);
  float v2 = hv.z + fmaxf(a2, 0.f);
  float v3 = hv.w + fmaxf(a3, 0.f);
  *reinterpret_cast<float4*>(hr) = make_float4(v0, v1, v2, v3);
  float s = wave_sum(v0 + v1 + v2 + v3);
  float mu = s * (1.f / 256.f);
  float q = (v0 - mu) * (v0 - mu) + (v1 - mu) * (v1 - mu) +
            (v2 - mu) * (v2 - mu) + (v3 - mu) * (v3 - mu);
  q = wave_sum(q);
  float is = rsqrtf(q * (1.f / 256.f) + 1e-5f);
  float4 gg = *reinterpret_cast<const float4*>(g + lane * 4);
  float4 bb = *reinterpret_cast<const float4*>(b + lane * 4);
  us4 out;
  out.x = f2bf((v0 - mu) * is * gg.x + bb.x);
  out.y = f2bf((v1 - mu) * is * gg.y + bb.y);
  out.z = f2bf((v2 - mu) * is * gg.z + bb.z);
  out.w = f2bf((v3 - mu) * is * gg.w + bb.w);
  *reinterpret_cast<us4*>(hn + (size_t)d * 256 + lane * 4) = out;
}

extern "C" void kernel_launch(void* const* d_in, const int* in_sizes, int n_in,
                              void* d_out, int out_size, void* d_ws, size_t ws_size,
                              hipStream_t stream) {
  const float* X   = (const float*)d_in[0];
  const int*   EI  = (const int*)d_in[1];
  const float* Wi  = (const float*)d_in[2];
  const float* bi  = (const float*)d_in[3];
  const float* wp  = (const float*)d_in[4];
  const float* Wa  = (const float*)d_in[5];
  const float* ba  = (const float*)d_in[6];
  const float* l1g = (const float*)d_in[7];
  const float* l1b = (const float*)d_in[8];
  const float* l2g = (const float*)d_in[9];
  const float* l2b = (const float*)d_in[10];
  const float* W1  = (const float*)d_in[11];
  const float* b1  = (const float*)d_in[12];
  const float* W2  = (const float*)d_in[13];
  const float* b2  = (const float*)d_in[14];
  const float* Wc  = (const float*)d_in[15];
  const float* bc  = (const float*)d_in[16];
  const float* Wo  = (const float*)d_in[17];
  const float* bo  = (const float*)d_in[18];

  const int N = in_sizes[0] / 256;
  const int E = in_sizes[1] / 2;
  const int Et = E + N;
  const int* srcp = EI;
  const int* dstp = EI + E;

  float* ws = (float*)d_ws;
  size_t off = 0;
  auto alloc = [&](size_t n) { float* p = ws + off; off += n; return p; };
  const size_t NH = (size_t)N * 256;
  float*  h    = alloc(NH);                            // f32 [N][256]
  ushort* hn   = (ushort*)alloc(NH / 2);               // bf16 [N][256] (also hb)
  ushort* xp   = (ushort*)alloc(NH / 2);               // bf16 [N][256]
  ushort* u    = (ushort*)alloc(NH);                   // bf16 [N][512]
  ushort* WcT  = (ushort*)alloc(3 * 65536 / 2);
  ushort* W1T  = (ushort*)alloc(3 * 131072 / 2);
  ushort* W2T  = (ushort*)alloc(3 * 131072 / 2);
  ushort* WoT  = (ushort*)alloc(16384 / 2);
  float* delta = alloc(N);
  float* adst  = alloc(N);
  float* asrc  = alloc(N);
  float* xwp   = alloc(N);
  float* expe  = alloc(Et);
  float* neigh = alloc(N);       // ┐ contiguous zero region (3N)
  float* denom = alloc(N);       // │
  int*   cnt   = (int*)alloc(N); // ┘
  int*   slots = (int*)alloc((size_t)N * 64);
  int*   kcnt  = (int*)alloc(N);
  int*   ksrc  = (int*)alloc((size_t)N * 8);
  float* kw    = alloc((size_t)N * 8);

  // weights + zeroing in one launch
  prep_k<<<(W_TOTAL + 3 * N + 255) / 256, 256, 0, stream>>>(
      Wc, W1, W2, Wo, WcT, W1T, W2T, WoT, neigh, 3 * N);

  // input projection + relu + row stats + LN1(layer0), all fused (f32-exact
  // top-k path)
  gemm_in<<<(N + 63) / 64, 256, 0, stream>>>(X, Wi, bi, Wa, wp, l1g, l1b,
                                             h, hn, delta, adst, asrc, xwp, N, 256);
  neigh_k<<<(E + 255) / 256, 256, 0, stream>>>(srcp, dstp, delta, neigh, E);
  logits_k<<<(Et + 255) / 256, 256, 0, stream>>>(srcp, dstp, adst, asrc, xwp, neigh,
                                                 Wa, ba, expe, denom, cnt, slots,
                                                 E, Et, N);
  topk_k<<<(N + 255) / 256, 256, 0, stream>>>(cnt, slots, expe, denom, srcp,
                                              kcnt, ksrc, kw, N, E);

  const int GM = (N + 127) / 128;
  for (int l = 0; l < 3; ++l) {
    gemm_mfma<1><<<dim3(GM, 2), 256, 0, stream>>>(
        hn, WcT + (size_t)l * 65536, bc + l * 256, xp, N, 256, 256);
    agg_ln_k<<<(N + 3) / 4, 256, 0, stream>>>(xp, kcnt, ksrc, kw,
                                              l2g + l * 256, l2b + l * 256, h, hn, N);
    gemm_mfma<2><<<dim3(GM, 4), 256, 0, stream>>>(
        hn, W1T + (size_t)l * 131072, b1 + l * 512, u, N, 512, 256);
    if (l < 2)
      gemm_ffn2<0><<<GM, 256, 0, stream>>>(
          u, W2T + (size_t)l * 131072, b2 + l * 256,
          l1g + (l + 1) * 256, l1b + (l + 1) * 256, h, hn, N);
    else
      gemm_ffn2<1><<<GM, 256, 0, stream>>>(
          u, W2T + (size_t)l * 131072, b2 + l * 256,
          nullptr, nullptr, h, hn, N);
  }
  // output projection (bf16 MFMA)
  gemm_out<<<(N + 127) / 128, 256, 0, stream>>>(hn, WoT, bo, (float*)d_out, N);
}

// Round 5
// 737.705 us; speedup vs baseline: 1.2107x; 1.2107x over previous
//
#include <hip/hip_runtime.h>
#include <math.h>

#define TAUF 0.9f

typedef unsigned int u32;
typedef unsigned short ushort;
typedef __attribute__((ext_vector_type(8))) short short8;
typedef __attribute__((ext_vector_type(8))) _Float16 half8;
typedef __attribute__((ext_vector_type(4))) _Float16 half4;
typedef __attribute__((ext_vector_type(4))) float f32x4;
typedef __attribute__((ext_vector_type(4))) unsigned short us4;

__device__ __forceinline__ float wave_sum(float v) {
#pragma unroll
  for (int off = 32; off > 0; off >>= 1) v += __shfl_down(v, off, 64);
  return __shfl(v, 0, 64);
}

__device__ __forceinline__ ushort f2bf(float f) {
  u32 u = __builtin_bit_cast(u32, f);
  u32 r = (u + 0x7FFFu + ((u >> 16) & 1u)) >> 16;
  return (ushort)r;
}
__device__ __forceinline__ float bf2f(ushort s) {
  u32 u = ((u32)s) << 16;
  return __builtin_bit_cast(float, u);
}

__device__ __forceinline__ void gload16(const void* g, void* l) {
  __builtin_amdgcn_global_load_lds(
      (const __attribute__((address_space(1))) u32*)g,
      (__attribute__((address_space(3))) u32*)l, 16, 0, 0);
}

// ---------- split-f16 input GEMM: h = relu(X @ Wi + bi), exact to ~f32 -------
// C = Ah@Bh + (Ah@Bl' + Al'@Bh)/2048, lo-parts pre-scaled by 2048 (no f16
// subnormals). BM=64, BN=256 (full row), BK=64, 4 waves (each 64r x 64c).
// Epilogue: h (f32), hn = LN1_l0(h) bf16, row stats delta/adst/asrc/xwp via
// cross-wave LDS reduce. LDS reused for staging then reduction.
__launch_bounds__(256, 2)
__global__ void gemm_in_mfma(const _Float16* __restrict__ Ah, const _Float16* __restrict__ Al,
                             const _Float16* __restrict__ Bh, const _Float16* __restrict__ Bl,
                             const float* __restrict__ bias, const float* __restrict__ Wa,
                             const float* __restrict__ wp, const float* __restrict__ g1,
                             const float* __restrict__ b1g, float* __restrict__ C,
                             ushort* __restrict__ hn, float* __restrict__ delta,
                             float* __restrict__ adst, float* __restrict__ asrc,
                             float* __restrict__ xwp, int M) {
  __shared__ char lds[81920];  // Ah 8K | Al 8K | Bh 32K | Bl 32K
  char* As_h = lds;
  char* As_l = lds + 8192;
  char* Bs_h = lds + 16384;
  char* Bs_l = lds + 49152;
  const int tid = threadIdx.x;
  const int wave = tid >> 6, lane = tid & 63;
  const int bm = blockIdx.x * 64;
  const int srow = lane >> 3;
  const int scol = (((lane & 7) ^ srow) << 3);

  f32x4 accH[4][4], accC[4][4];
#pragma unroll
  for (int i = 0; i < 4; ++i)
#pragma unroll
    for (int j = 0; j < 4; ++j) {
      accH[i][j] = (f32x4){0.f, 0.f, 0.f, 0.f};
      accC[i][j] = (f32x4){0.f, 0.f, 0.f, 0.f};
    }

  for (int k0 = 0; k0 < 256; k0 += 64) {
#pragma unroll
    for (int r = 0; r < 2; ++r) {
      const int ch = r * 4 + wave;
      int ar = bm + ch * 8 + srow;
      ar = (ar < M) ? ar : (M - 1);
      gload16(Ah + (size_t)ar * 256 + k0 + scol, As_h + ch * 1024);
      gload16(Al + (size_t)ar * 256 + k0 + scol, As_l + ch * 1024);
    }
#pragma unroll
    for (int r = 0; r < 8; ++r) {
      const int ch = r * 4 + wave;
      const int br = ch * 8 + srow;
      gload16(Bh + (size_t)br * 256 + k0 + scol, Bs_h + ch * 1024);
      gload16(Bl + (size_t)br * 256 + k0 + scol, Bs_l + ch * 1024);
    }
    __syncthreads();
#pragma unroll
    for (int kk = 0; kk < 2; ++kk) {
      const int c = (kk * 32 + (lane >> 4) * 8) * 2;
      half8 ah[4], bh[4];
#pragma unroll
      for (int mi = 0; mi < 4; ++mi) {
        const int rr = mi * 16 + (lane & 15);
        ah[mi] = *(const half8*)(As_h + rr * 128 + (c ^ ((rr & 7) << 4)));
      }
#pragma unroll
      for (int ni = 0; ni < 4; ++ni) {
        const int rr = wave * 64 + ni * 16 + (lane & 15);
        bh[ni] = *(const half8*)(Bs_h + rr * 128 + (c ^ ((rr & 7) << 4)));
      }
#pragma unroll
      for (int mi = 0; mi < 4; ++mi)
#pragma unroll
        for (int ni = 0; ni < 4; ++ni)
          accH[mi][ni] = __builtin_amdgcn_mfma_f32_16x16x32_f16(ah[mi], bh[ni],
                                                                accH[mi][ni], 0, 0, 0);
      half8 al[4];
#pragma unroll
      for (int mi = 0; mi < 4; ++mi) {
        const int rr = mi * 16 + (lane & 15);
        al[mi] = *(const half8*)(As_l + rr * 128 + (c ^ ((rr & 7) << 4)));
      }
#pragma unroll
      for (int mi = 0; mi < 4; ++mi)
#pragma unroll
        for (int ni = 0; ni < 4; ++ni)
          accC[mi][ni] = __builtin_amdgcn_mfma_f32_16x16x32_f16(al[mi], bh[ni],
                                                                accC[mi][ni], 0, 0, 0);
      half8 bl[4];
#pragma unroll
      for (int ni = 0; ni < 4; ++ni) {
        const int rr = wave * 64 + ni * 16 + (lane & 15);
        bl[ni] = *(const half8*)(Bs_l + rr * 128 + (c ^ ((rr & 7) << 4)));
      }
#pragma unroll
      for (int mi = 0; mi < 4; ++mi)
#pragma unroll
        for (int ni = 0; ni < 4; ++ni)
          accC[mi][ni] = __builtin_amdgcn_mfma_f32_16x16x32_f16(ah[mi], bl[ni],
                                                                accC[mi][ni], 0, 0, 0);
    }
    __syncthreads();
  }

  // epilogue: v = accH + accC/2048 + bias, relu; stats; LN1(l0)
  float bb[4], wa0[4], wa1[4], wpv[4], gg[4], gb[4];
#pragma unroll
  for (int ni = 0; ni < 4; ++ni) {
    const int c = wave * 64 + ni * 16 + (lane & 15);
    bb[ni] = bias[c]; wa0[ni] = Wa[c]; wa1[ni] = Wa[256 + c];
    wpv[ni] = wp[c]; gg[ni] = g1[c]; gb[ni] = b1g[c];
  }
  float* red = (float*)lds;              // [5][4 waves][64 rows] = 5120 B
  float* muA = (float*)(lds + 5120);     // [64]
  float* isA = (float*)(lds + 5376);     // [64]
  const float inv = 1.f / 2048.f;
#pragma unroll
  for (int mi = 0; mi < 4; ++mi) {
#pragma unroll
    for (int reg = 0; reg < 4; ++reg) {
      const int lrow = mi * 16 + (lane >> 4) * 4 + reg;
      const int row = bm + lrow;
      float v[4];
      float p0 = 0.f, p1 = 0.f, p2 = 0.f, p3 = 0.f, p4 = 0.f;
#pragma unroll
      for (int ni = 0; ni < 4; ++ni) {
        float t = accH[mi][ni][reg] + accC[mi][ni][reg] * inv + bb[ni];
        t = fmaxf(t, 0.f);
        v[ni] = t;
        p0 += t; p1 += t * wa0[ni]; p2 += t * wa1[ni]; p3 += t * wpv[ni];
        p4 += t * t;
      }
      if (row < M) {
#pragma unroll
        for (int ni = 0; ni < 4; ++ni)
          C[(size_t)row * 256 + wave * 64 + ni * 16 + (lane & 15)] = v[ni];
      }
#pragma unroll
      for (int ni = 0; ni < 4; ++ni) accH[mi][ni][reg] = v[ni];
#pragma unroll
      for (int off = 1; off < 16; off <<= 1) {
        p0 += __shfl_xor(p0, off, 64);
        p1 += __shfl_xor(p1, off, 64);
        p2 += __shfl_xor(p2, off, 64);
        p3 += __shfl_xor(p3, off, 64);
        p4 += __shfl_xor(p4, off, 64);
      }
      if ((lane & 15) == 0) {
        red[(0 * 4 + wave) * 64 + lrow] = p0;
        red[(1 * 4 + wave) * 64 + lrow] = p1;
        red[(2 * 4 + wave) * 64 + lrow] = p2;
        red[(3 * 4 + wave) * 64 + lrow] = p3;
        red[(4 * 4 + wave) * 64 + lrow] = p4;
      }
    }
  }
  __syncthreads();
  if (tid < 64) {
    float s0 = 0.f, s1 = 0.f, s2 = 0.f, s3 = 0.f, s4 = 0.f;
#pragma unroll
    for (int w = 0; w < 4; ++w) {
      s0 += red[(0 * 4 + w) * 64 + tid];
      s1 += red[(1 * 4 + w) * 64 + tid];
      s2 += red[(2 * 4 + w) * 64 + tid];
      s3 += red[(3 * 4 + w) * 64 + tid];
      s4 += red[(4 * 4 + w) * 64 + tid];
    }
    const int row = bm + tid;
    if (row < M) {
      delta[row] = s0; adst[row] = s1; asrc[row] = s2; xwp[row] = s3;
    }
    float mu = s0 * (1.f / 256.f);
    muA[tid] = mu;
    isA[tid] = rsqrtf(s4 * (1.f / 256.f) - mu * mu + 1e-5f);
  }
  __syncthreads();
#pragma unroll
  for (int mi = 0; mi < 4; ++mi) {
#pragma unroll
    for (int reg = 0; reg < 4; ++reg) {
      const int lrow = mi * 16 + (lane >> 4) * 4 + reg;
      const int row = bm + lrow;
      if (row >= M) continue;
      const float mu = muA[lrow], is = isA[lrow];
#pragma unroll
      for (int ni = 0; ni < 4; ++ni) {
        const int col = wave * 64 + ni * 16 + (lane & 15);
        hn[(size_t)row * 256 + col] = f2bf((accH[mi][ni][reg] - mu) * is * gg[ni] + gb[ni]);
      }
    }
  }
}

// X [M][256] f32 -> Xh, Xl (f16, lo scaled 2048)
__global__ void xsplit_k(const float* __restrict__ X, _Float16* __restrict__ Xh,
                         _Float16* __restrict__ Xl, int total4) {
  int i = blockIdx.x * 256 + threadIdx.x;
  if (i >= total4) return;
  float4 x = reinterpret_cast<const float4*>(X)[i];
  half4 h, l;
  float xs[4] = {x.x, x.y, x.z, x.w};
#pragma unroll
  for (int j = 0; j < 4; ++j) {
    _Float16 hv = (_Float16)xs[j];
    h[j] = hv;
    l[j] = (_Float16)((xs[j] - (float)hv) * 2048.f);
  }
  reinterpret_cast<half4*>(Xh)[i] = h;
  reinterpret_cast<half4*>(Xl)[i] = l;
}

// ---------------- bf16 MFMA GEMM: C = epi(A @ Bt^T + bias) -------------------
// EPI: 1 bias->bf16, 2 bias+gelu->bf16, 3 bias+residual RMW on f32 Cf,
//      4 bias + Cf(read) -> bf16 Cb.  BM=BN=128, BK=64, 4 waves.
template <int EPI>
__launch_bounds__(256)
__global__ void gemm_mfma(const ushort* __restrict__ A, const ushort* __restrict__ Bt,
                          const float* __restrict__ bias, float* __restrict__ Cf,
                          ushort* __restrict__ Cb, int M, int N, int K) {
  __shared__ ushort As[128 * 64];
  __shared__ ushort Bs[128 * 64];
  const int tid = threadIdx.x;
  const int wave = tid >> 6, lane = tid & 63;
  const int bm = blockIdx.x * 128, bn = blockIdx.y * 128;
  const int wm = (wave >> 1) * 64, wn = (wave & 1) * 64;
  const int srow = lane >> 3;
  const int scol = (((lane & 7) ^ srow) << 3);

  f32x4 acc[4][4];
#pragma unroll
  for (int i = 0; i < 4; ++i)
#pragma unroll
    for (int j = 0; j < 4; ++j) acc[i][j] = (f32x4){0.f, 0.f, 0.f, 0.f};

  for (int k0 = 0; k0 < K; k0 += 64) {
#pragma unroll
    for (int r = 0; r < 4; ++r) {
      const int ch = r * 4 + wave;
      int ar = bm + ch * 8 + srow;
      ar = (ar < M) ? ar : (M - 1);
      gload16(A + (size_t)ar * K + k0 + scol, (char*)As + ch * 1024);
      const int br = bn + ch * 8 + srow;
      gload16(Bt + (size_t)br * K + k0 + scol, (char*)Bs + ch * 1024);
    }
    __syncthreads();
#pragma unroll
    for (int kk = 0; kk < 2; ++kk) {
      const int c = (kk * 32 + (lane >> 4) * 8) * 2;
      short8 a[4];
#pragma unroll
      for (int mi = 0; mi < 4; ++mi) {
        const int rr = wm + mi * 16 + (lane & 15);
        a[mi] = *(const short8*)((const char*)As + rr * 128 + (c ^ ((rr & 7) << 4)));
      }
#pragma unroll
      for (int ni = 0; ni < 4; ++ni) {
        const int rr = wn + ni * 16 + (lane & 15);
        short8 b = *(const short8*)((const char*)Bs + rr * 128 + (c ^ ((rr & 7) << 4)));
#pragma unroll
        for (int mi = 0; mi < 4; ++mi)
          acc[mi][ni] = __builtin_amdgcn_mfma_f32_16x16x32_bf16(a[mi], b,
                                                                acc[mi][ni], 0, 0, 0);
      }
    }
    __syncthreads();
  }

  float bb[4];
#pragma unroll
  for (int ni = 0; ni < 4; ++ni) bb[ni] = bias[bn + wn + ni * 16 + (lane & 15)];
#pragma unroll
  for (int mi = 0; mi < 4; ++mi) {
#pragma unroll
    for (int reg = 0; reg < 4; ++reg) {
      const int row = bm + wm + mi * 16 + (lane >> 4) * 4 + reg;
      if (row >= M) continue;
#pragma unroll
      for (int ni = 0; ni < 4; ++ni) {
        const int col = bn + wn + ni * 16 + (lane & 15);
        float v = acc[mi][ni][reg] + bb[ni];
        if (EPI == 1) {
          Cb[(size_t)row * N + col] = f2bf(v);
        } else if (EPI == 2) {
          v = v * 0.5f * (1.f + erff(v * 0.70710678118654752f));
          Cb[(size_t)row * N + col] = f2bf(v);
        } else if (EPI == 3) {
          Cf[(size_t)row * N + col] += v;
        } else {  // EPI == 4
          v += Cf[(size_t)row * N + col];
          Cb[(size_t)row * N + col] = f2bf(v);
        }
      }
    }
  }
}

// ---------------- bf16 MFMA output GEMM: C(f32) = A @ Bt^T + bias ------------
__launch_bounds__(256)
__global__ void gemm_out(const ushort* __restrict__ A, const ushort* __restrict__ Bt,
                         const float* __restrict__ bias, float* __restrict__ C, int M) {
  __shared__ ushort As[128 * 64];
  __shared__ ushort Bs[64 * 64];
  const int tid = threadIdx.x;
  const int wave = tid >> 6, lane = tid & 63;
  const int bm = blockIdx.x * 128;
  const int wm = wave * 32;
  const int srow = lane >> 3;
  const int scol = (((lane & 7) ^ srow) << 3);
  f32x4 acc[2][4];
#pragma unroll
  for (int i = 0; i < 2; ++i)
#pragma unroll
    for (int j = 0; j < 4; ++j) acc[i][j] = (f32x4){0.f, 0.f, 0.f, 0.f};

  for (int k0 = 0; k0 < 256; k0 += 64) {
#pragma unroll
    for (int r = 0; r < 4; ++r) {
      const int ch = r * 4 + wave;
      int ar = bm + ch * 8 + srow;
      ar = (ar < M) ? ar : (M - 1);
      gload16(A + (size_t)ar * 256 + k0 + scol, (char*)As + ch * 1024);
    }
#pragma unroll
    for (int r = 0; r < 2; ++r) {
      const int ch = r * 4 + wave;
      const int br = ch * 8 + srow;
      gload16(Bt + (size_t)br * 256 + k0 + scol, (char*)Bs + ch * 1024);
    }
    __syncthreads();
#pragma unroll
    for (int kk = 0; kk < 2; ++kk) {
      const int c = (kk * 32 + (lane >> 4) * 8) * 2;
      short8 a[2], b[4];
#pragma unroll
      for (int mi = 0; mi < 2; ++mi) {
        const int rr = wm + mi * 16 + (lane & 15);
        a[mi] = *(const short8*)((const char*)As + rr * 128 + (c ^ ((rr & 7) << 4)));
      }
#pragma unroll
      for (int ni = 0; ni < 4; ++ni) {
        const int rr = ni * 16 + (lane & 15);
        b[ni] = *(const short8*)((const char*)Bs + rr * 128 + (c ^ ((rr & 7) << 4)));
      }
#pragma unroll
      for (int mi = 0; mi < 2; ++mi)
#pragma unroll
        for (int ni = 0; ni < 4; ++ni)
          acc[mi][ni] = __builtin_amdgcn_mfma_f32_16x16x32_bf16(a[mi], b[ni],
                                                                acc[mi][ni], 0, 0, 0);
    }
    __syncthreads();
  }
  float bb[4];
#pragma unroll
  for (int ni = 0; ni < 4; ++ni) bb[ni] = bias[ni * 16 + (lane & 15)];
#pragma unroll
  for (int mi = 0; mi < 2; ++mi) {
#pragma unroll
    for (int reg = 0; reg < 4; ++reg) {
      const int row = bm + wm + mi * 16 + (lane >> 4) * 4 + reg;
      if (row >= M) continue;
#pragma unroll
      for (int ni = 0; ni < 4; ++ni) {
        const int col = ni * 16 + (lane & 15);
        C[(size_t)row * 64 + col] = acc[mi][ni][reg] + bb[ni];
      }
    }
  }
}

// ---- one-shot prep: weight transposes/converts (incl. Wi f16 split) + zero --
#define W_IN 65536
#define W_TOTAL (196608 + 393216 + 393216 + 16384)
__global__ void prep_k(const float* __restrict__ Wi, const float* __restrict__ Wc,
                       const float* __restrict__ W1, const float* __restrict__ W2,
                       const float* __restrict__ Wo, _Float16* __restrict__ WiTh,
                       _Float16* __restrict__ WiTl, ushort* __restrict__ WcT,
                       ushort* __restrict__ W1T, ushort* __restrict__ W2T,
                       ushort* __restrict__ WoT, float* __restrict__ zbase, int zn) {
  int i = blockIdx.x * 256 + threadIdx.x;
  if (i < W_IN) {
    int n = i >> 8, k = i & 255;
    float w = Wi[(size_t)k * 256 + n];
    _Float16 hv = (_Float16)w;
    WiTh[i] = hv;
    WiTl[i] = (_Float16)((w - (float)hv) * 2048.f);
  } else if ((i -= W_IN) < W_TOTAL) {
    int j = i;
    if (j < 196608) {
      int l = j / 65536, r = j % 65536, n = r >> 8, k = r & 255;
      WcT[j] = f2bf(Wc[(size_t)l * 65536 + k * 256 + n]);
    } else if ((j -= 196608) < 393216) {
      int l = j / 131072, r = j % 131072, n = r >> 8, k = r & 255;
      W1T[j] = f2bf(W1[(size_t)l * 131072 + k * 512 + n]);
    } else if ((j -= 393216) < 393216) {
      int l = j / 131072, r = j % 131072, n = r >> 9, k = r & 511;
      W2T[j] = f2bf(W2[(size_t)l * 131072 + k * 256 + n]);
    } else {
      j -= 393216;
      int n = j >> 8, k = j & 255;
      WoT[j] = f2bf(Wo[k * 64 + n]);
    }
  } else {
    int z = i - W_TOTAL;
    if (z < zn) zbase[z] = 0.f;
  }
}

__global__ void neigh_k(const int* __restrict__ src, const int* __restrict__ dst,
                        const float* __restrict__ delta, float* __restrict__ neigh, int E) {
  int e = blockIdx.x * 256 + threadIdx.x;
  if (e < E) atomicAdd(&neigh[dst[e]], delta[src[e]]);
}

// edge logits (pi inline); slots layout [t][N]
__global__ void logits_k(const int* __restrict__ src, const int* __restrict__ dst,
                         const float* __restrict__ adst, const float* __restrict__ asrc,
                         const float* __restrict__ xwp, const float* __restrict__ neigh,
                         const float* __restrict__ Wa, const float* __restrict__ ba,
                         float* __restrict__ expe, float* __restrict__ denom,
                         int* __restrict__ cnt, int* __restrict__ slots,
                         int E, int Et, int N) {
  int e = blockIdx.x * 256 + threadIdx.x;
  if (e >= Et) return;
  int s, d;
  if (e < E) { s = src[e]; d = dst[e]; } else { s = e - E; d = s; }
  float pis = 1.f / (1.f + expf(-(xwp[s] + neigh[s])));
  float v = adst[d] + asrc[s] + pis * Wa[512] + ba[0];
  v = (v >= 0.f ? v : 0.2f * v) / TAUF;
  v = fminf(fmaxf(v, -5.f), 5.f);
  float ex = expf(v);
  expe[e] = ex;
  atomicAdd(&denom[d], ex);
  int p = atomicAdd(&cnt[d], 1);
  if (p < 64) slots[(size_t)p * N + d] = e;
}

__device__ __forceinline__ bool better(float a, int e, float a2, int e2) {
  return a > a2 || (a == a2 && e < e2);
}

__global__ void topk_k(const int* __restrict__ cnt, const int* __restrict__ slots,
                       const float* __restrict__ expe, const float* __restrict__ denom,
                       const int* __restrict__ src, int* __restrict__ kcnt,
                       int* __restrict__ ksrc, float* __restrict__ kw, int N, int E) {
  int d = blockIdx.x * 256 + threadIdx.x;
  if (d >= N) return;
  int deg = min(cnt[d], 64);
  float D = denom[d] + 1e-16f;
  float av[8]; int ai[8]; int kc = 0;
  for (int t = 0; t < deg; ++t) {
    int e = slots[(size_t)t * N + d];
    float a = expe[e] / D;
    if (kc < 8) {
      int p = kc++;
      while (p > 0 && better(a, e, av[p - 1], ai[p - 1])) {
        av[p] = av[p - 1]; ai[p] = ai[p - 1]; --p;
      }
      av[p] = a; ai[p] = e;
    } else if (better(a, e, av[7], ai[7])) {
      int p = 7;
      while (p > 0 && better(a, e, av[p - 1], ai[p - 1])) {
        av[p] = av[p - 1]; ai[p] = ai[p - 1]; --p;
      }
      av[p] = a; ai[p] = e;
    }
  }
  float ks = 0.f;
  for (int j = 0; j < kc; ++j) ks += av[j];
  kcnt[d] = kc;
  for (int j = 0; j < kc; ++j) {
    int e = ai[j];
    ksrc[(size_t)d * 8 + j] = (e < E) ? src[e] : (e - E);
    kw[(size_t)d * 8 + j] = av[j] / (ks + 1e-16f);
  }
}

// LayerNorm (reads f32 h, writes bf16)
__global__ void ln_k(const float* __restrict__ h, const float* __restrict__ g,
                     const float* __restrict__ b, ushort* __restrict__ o, int N) {
  int row = blockIdx.x * 4 + (threadIdx.x >> 6);
  if (row >= N) return;
  int lane = threadIdx.x & 63;
  float4 v = *reinterpret_cast<const float4*>(h + (size_t)row * 256 + lane * 4);
  float s = wave_sum(v.x + v.y + v.z + v.w);
  float mu = s * (1.f / 256.f);
  float q = (v.x - mu) * (v.x - mu) + (v.y - mu) * (v.y - mu) +
            (v.z - mu) * (v.z - mu) + (v.w - mu) * (v.w - mu);
  q = wave_sum(q);
  float is = rsqrtf(q * (1.f / 256.f) + 1e-5f);
  float4 gg = *reinterpret_cast<const float4*>(g + lane * 4);
  float4 bb = *reinterpret_cast<const float4*>(b + lane * 4);
  us4 out;
  out.x = f2bf((v.x - mu) * is * gg.x + bb.x);
  out.y = f2bf((v.y - mu) * is * gg.y + bb.y);
  out.z = f2bf((v.z - mu) * is * gg.z + bb.z);
  out.w = f2bf((v.w - mu) * is * gg.w + bb.w);
  *reinterpret_cast<us4*>(o + (size_t)row * 256 + lane * 4) = out;
}

// fused: h += relu(sum_j kw*xp[ksrc]); then LN2 -> hn (bf16). One wave per row.
__global__ void agg_ln_k(const ushort* __restrict__ xp, const int* __restrict__ kcnt,
                         const int* __restrict__ ksrc, const float* __restrict__ kw,
                         const float* __restrict__ g, const float* __restrict__ b,
                         float* __restrict__ h, ushort* __restrict__ hn, int N) {
  int d = blockIdx.x * 4 + (threadIdx.x >> 6);
  if (d >= N) return;
  int lane = threadIdx.x & 63;
  int kc = kcnt[d];
  float a0 = 0.f, a1 = 0.f, a2 = 0.f, a3 = 0.f;
  for (int j = 0; j < kc; ++j) {
    int s = ksrc[(size_t)d * 8 + j];
    float w = kw[(size_t)d * 8 + j];
    us4 xv = *reinterpret_cast<const us4*>(xp + (size_t)s * 256 + lane * 4);
    a0 += w * bf2f(xv.x);
    a1 += w * bf2f(xv.y);
    a2 += w * bf2f(xv.z);
    a3 += w * bf2f(xv.w);
  }
  float* hr = h + (size_t)d * 256 + lane * 4;
  float4 hv = *reinterpret_cast<const float4*>(hr);
  float v0 = hv.x + fmaxf(a0, 0.f);
  float v1 = hv.y + fmaxf(a1, 0.f);
  float v2 = hv.z + fmaxf(a2, 0.f);
  float v3 = hv.w + fmaxf(a3, 0.f);
  *reinterpret_cast<float4*>(hr) = make_float4(v0, v1, v2, v3);
  float s = wave_sum(v0 + v1 + v2 + v3);
  float mu = s * (1.f / 256.f);
  float q = (v0 - mu) * (v0 - mu) + (v1 - mu) * (v1 - mu) +
            (v2 - mu) * (v2 - mu) + (v3 - mu) * (v3 - mu);
  q = wave_sum(q);
  float is = rsqrtf(q * (1.f / 256.f) + 1e-5f);
  float4 gg = *reinterpret_cast<const float4*>(g + lane * 4);
  float4 bb = *reinterpret_cast<const float4*>(b + lane * 4);
  us4 out;
  out.x = f2bf((v0 - mu) * is * gg.x + bb.x);
  out.y = f2bf((v1 - mu) * is * gg.y + bb.y);
  out.z = f2bf((v2 - mu) * is * gg.z + bb.z);
  out.w = f2bf((v3 - mu) * is * gg.w + bb.w);
  *reinterpret_cast<us4*>(hn + (size_t)d * 256 + lane * 4) = out;
}

extern "C" void kernel_launch(void* const* d_in, const int* in_sizes, int n_in,
                              void* d_out, int out_size, void* d_ws, size_t ws_size,
                              hipStream_t stream) {
  const float* X   = (const float*)d_in[0];
  const int*   EI  = (const int*)d_in[1];
  const float* Wi  = (const float*)d_in[2];
  const float* bi  = (const float*)d_in[3];
  const float* wp  = (const float*)d_in[4];
  const float* Wa  = (const float*)d_in[5];
  const float* ba  = (const float*)d_in[6];
  const float* l1g = (const float*)d_in[7];
  const float* l1b = (const float*)d_in[8];
  const float* l2g = (const float*)d_in[9];
  const float* l2b = (const float*)d_in[10];
  const float* W1  = (const float*)d_in[11];
  const float* b1  = (const float*)d_in[12];
  const float* W2  = (const float*)d_in[13];
  const float* b2  = (const float*)d_in[14];
  const float* Wc  = (const float*)d_in[15];
  const float* bc  = (const float*)d_in[16];
  const float* Wo  = (const float*)d_in[17];
  const float* bo  = (const float*)d_in[18];

  const int N = in_sizes[0] / 256;
  const int E = in_sizes[1] / 2;
  const int Et = E + N;
  const int* srcp = EI;
  const int* dstp = EI + E;

  float* ws = (float*)d_ws;
  size_t off = 0;
  auto alloc = [&](size_t n) { float* p = ws + off; off += n; return p; };
  const size_t NH = (size_t)N * 256;
  float*  h    = alloc(NH);                            // f32 [N][256]
  ushort* hn   = (ushort*)alloc(NH / 2);               // bf16 [N][256] (also hb)
  ushort* xp   = (ushort*)alloc(NH / 2);               // bf16 [N][256]
  float*  ualias = alloc(NH);                          // u (bf16 [N][512]) / Xh+Xl (f16)
  ushort* u    = (ushort*)ualias;
  _Float16* Xh = (_Float16*)ualias;                    // f16 [N][256]
  _Float16* Xl = Xh + NH;                              // f16 [N][256]
  _Float16* WiTh = (_Float16*)alloc(65536 / 2);
  _Float16* WiTl = (_Float16*)alloc(65536 / 2);
  ushort* WcT  = (ushort*)alloc(3 * 65536 / 2);
  ushort* W1T  = (ushort*)alloc(3 * 131072 / 2);
  ushort* W2T  = (ushort*)alloc(3 * 131072 / 2);
  ushort* WoT  = (ushort*)alloc(16384 / 2);
  float* delta = alloc(N);
  float* adst  = alloc(N);
  float* asrc  = alloc(N);
  float* xwp   = alloc(N);
  float* expe  = alloc(Et);
  float* neigh = alloc(N);       // ┐ contiguous zero region (3N)
  float* denom = alloc(N);       // │
  int*   cnt   = (int*)alloc(N); // ┘
  int*   slots = (int*)alloc((size_t)N * 64);
  int*   kcnt  = (int*)alloc(N);
  int*   ksrc  = (int*)alloc((size_t)N * 8);
  float* kw    = alloc((size_t)N * 8);

  // weights (incl. Wi f16 split) + zeroing
  prep_k<<<(W_IN + W_TOTAL + 3 * N + 255) / 256, 256, 0, stream>>>(
      Wi, Wc, W1, W2, Wo, WiTh, WiTl, WcT, W1T, W2T, WoT, neigh, 3 * N);
  // X f16 split
  xsplit_k<<<((int)(NH / 4) + 255) / 256, 256, 0, stream>>>(X, Xh, Xl, (int)(NH / 4));

  // input projection + relu + row stats + LN1(layer0), split-f16 MFMA
  gemm_in_mfma<<<(N + 63) / 64, 256, 0, stream>>>(
      Xh, Xl, WiTh, WiTl, bi, Wa, wp, l1g, l1b, h, hn,
      delta, adst, asrc, xwp, N);
  neigh_k<<<(E + 255) / 256, 256, 0, stream>>>(srcp, dstp, delta, neigh, E);
  logits_k<<<(Et + 255) / 256, 256, 0, stream>>>(srcp, dstp, adst, asrc, xwp, neigh,
                                                 Wa, ba, expe, denom, cnt, slots,
                                                 E, Et, N);
  topk_k<<<(N + 255) / 256, 256, 0, stream>>>(cnt, slots, expe, denom, srcp,
                                              kcnt, ksrc, kw, N, E);

  const int GM = (N + 127) / 128;
  for (int l = 0; l < 3; ++l) {
    gemm_mfma<1><<<dim3(GM, 2), 256, 0, stream>>>(
        hn, WcT + (size_t)l * 65536, bc + l * 256, nullptr, xp, N, 256, 256);
    agg_ln_k<<<(N + 3) / 4, 256, 0, stream>>>(xp, kcnt, ksrc, kw,
                                              l2g + l * 256, l2b + l * 256, h, hn, N);
    gemm_mfma<2><<<dim3(GM, 4), 256, 0, stream>>>(
        hn, W1T + (size_t)l * 131072, b1 + l * 512, nullptr, u, N, 512, 256);
    if (l < 2) {
      gemm_mfma<3><<<dim3(GM, 2), 256, 0, stream>>>(
          u, W2T + (size_t)l * 131072, b2 + l * 256, h, nullptr, N, 256, 512);
      ln_k<<<(N + 3) / 4, 256, 0, stream>>>(h, l1g + (l + 1) * 256,
                                            l1b + (l + 1) * 256, hn, N);
    } else {
      gemm_mfma<4><<<dim3(GM, 2), 256, 0, stream>>>(
          u, W2T + (size_t)l * 131072, b2 + l * 256, h, hn, N, 256, 512);
    }
  }
  // output projection (bf16 MFMA)
  gemm_out<<<(N + 127) / 128, 256, 0, stream>>>(hn, WoT, bo, (float*)d_out, N);
}

// Round 6
// 676.847 us; speedup vs baseline: 1.3196x; 1.0899x over previous
//
#include <hip/hip_runtime.h>
#include <math.h>

#define TAUF 0.9f

typedef unsigned int u32;
typedef unsigned short ushort;
typedef __attribute__((ext_vector_type(8))) short short8;
typedef __attribute__((ext_vector_type(8))) _Float16 half8;
typedef __attribute__((ext_vector_type(4))) _Float16 half4;
typedef __attribute__((ext_vector_type(4))) float f32x4;
typedef __attribute__((ext_vector_type(4))) unsigned short us4;

__device__ __forceinline__ float wave_sum(float v) {
#pragma unroll
  for (int off = 32; off > 0; off >>= 1) v += __shfl_down(v, off, 64);
  return __shfl(v, 0, 64);
}

__device__ __forceinline__ ushort f2bf(float f) {
  u32 u = __builtin_bit_cast(u32, f);
  u32 r = (u + 0x7FFFu + ((u >> 16) & 1u)) >> 16;
  return (ushort)r;
}
__device__ __forceinline__ float bf2f(ushort s) {
  u32 u = ((u32)s) << 16;
  return __builtin_bit_cast(float, u);
}

// exact-form GELU via A&S 7.1.26 erf approx (|erf err| < 1.5e-7)
__device__ __forceinline__ float gelu_f(float x) {
  float z = x * 0.70710678118654752f;
  float az = fabsf(z);
  float t = 1.f / fmaf(0.3275911f, az, 1.f);
  float poly = t * fmaf(t, fmaf(t, fmaf(t, fmaf(t, 1.061405429f, -1.453152027f),
                                        1.421413741f), -0.284496736f), 0.254829592f);
  float erfa = fmaf(-poly, __expf(-az * az), 1.f);
  float s = (z < 0.f) ? -erfa : erfa;
  return 0.5f * x * (1.f + s);
}

__device__ __forceinline__ void gload16(const void* g, void* l) {
  __builtin_amdgcn_global_load_lds(
      (const __attribute__((address_space(1))) u32*)g,
      (__attribute__((address_space(3))) u32*)l, 16, 0, 0);
}

// ---------- split-f16 input GEMM: h = relu(X @ Wi + bi), exact to ~f32 -------
__launch_bounds__(256, 2)
__global__ void gemm_in_mfma(const _Float16* __restrict__ Ah, const _Float16* __restrict__ Al,
                             const _Float16* __restrict__ Bh, const _Float16* __restrict__ Bl,
                             const float* __restrict__ bias, const float* __restrict__ Wa,
                             const float* __restrict__ wp, const float* __restrict__ g1,
                             const float* __restrict__ b1g, float* __restrict__ C,
                             ushort* __restrict__ hn, float* __restrict__ delta,
                             float* __restrict__ adst, float* __restrict__ asrc,
                             float* __restrict__ xwp, int M) {
  __shared__ char lds[81920];  // Ah 8K | Al 8K | Bh 32K | Bl 32K
  char* As_h = lds;
  char* As_l = lds + 8192;
  char* Bs_h = lds + 16384;
  char* Bs_l = lds + 49152;
  const int tid = threadIdx.x;
  const int wave = tid >> 6, lane = tid & 63;
  const int bm = blockIdx.x * 64;
  const int srow = lane >> 3;
  const int scol = (((lane & 7) ^ srow) << 3);

  f32x4 accH[4][4], accC[4][4];
#pragma unroll
  for (int i = 0; i < 4; ++i)
#pragma unroll
    for (int j = 0; j < 4; ++j) {
      accH[i][j] = (f32x4){0.f, 0.f, 0.f, 0.f};
      accC[i][j] = (f32x4){0.f, 0.f, 0.f, 0.f};
    }

  for (int k0 = 0; k0 < 256; k0 += 64) {
#pragma unroll
    for (int r = 0; r < 2; ++r) {
      const int ch = r * 4 + wave;
      int ar = bm + ch * 8 + srow;
      ar = (ar < M) ? ar : (M - 1);
      gload16(Ah + (size_t)ar * 256 + k0 + scol, As_h + ch * 1024);
      gload16(Al + (size_t)ar * 256 + k0 + scol, As_l + ch * 1024);
    }
#pragma unroll
    for (int r = 0; r < 8; ++r) {
      const int ch = r * 4 + wave;
      const int br = ch * 8 + srow;
      gload16(Bh + (size_t)br * 256 + k0 + scol, Bs_h + ch * 1024);
      gload16(Bl + (size_t)br * 256 + k0 + scol, Bs_l + ch * 1024);
    }
    __syncthreads();
#pragma unroll
    for (int kk = 0; kk < 2; ++kk) {
      const int c = (kk * 32 + (lane >> 4) * 8) * 2;
      half8 ah[4], bh[4];
#pragma unroll
      for (int mi = 0; mi < 4; ++mi) {
        const int rr = mi * 16 + (lane & 15);
        ah[mi] = *(const half8*)(As_h + rr * 128 + (c ^ ((rr & 7) << 4)));
      }
#pragma unroll
      for (int ni = 0; ni < 4; ++ni) {
        const int rr = wave * 64 + ni * 16 + (lane & 15);
        bh[ni] = *(const half8*)(Bs_h + rr * 128 + (c ^ ((rr & 7) << 4)));
      }
#pragma unroll
      for (int mi = 0; mi < 4; ++mi)
#pragma unroll
        for (int ni = 0; ni < 4; ++ni)
          accH[mi][ni] = __builtin_amdgcn_mfma_f32_16x16x32_f16(ah[mi], bh[ni],
                                                                accH[mi][ni], 0, 0, 0);
      half8 al[4];
#pragma unroll
      for (int mi = 0; mi < 4; ++mi) {
        const int rr = mi * 16 + (lane & 15);
        al[mi] = *(const half8*)(As_l + rr * 128 + (c ^ ((rr & 7) << 4)));
      }
#pragma unroll
      for (int mi = 0; mi < 4; ++mi)
#pragma unroll
        for (int ni = 0; ni < 4; ++ni)
          accC[mi][ni] = __builtin_amdgcn_mfma_f32_16x16x32_f16(al[mi], bh[ni],
                                                                accC[mi][ni], 0, 0, 0);
      half8 bl[4];
#pragma unroll
      for (int ni = 0; ni < 4; ++ni) {
        const int rr = wave * 64 + ni * 16 + (lane & 15);
        bl[ni] = *(const half8*)(Bs_l + rr * 128 + (c ^ ((rr & 7) << 4)));
      }
#pragma unroll
      for (int mi = 0; mi < 4; ++mi)
#pragma unroll
        for (int ni = 0; ni < 4; ++ni)
          accC[mi][ni] = __builtin_amdgcn_mfma_f32_16x16x32_f16(ah[mi], bl[ni],
                                                                accC[mi][ni], 0, 0, 0);
    }
    __syncthreads();
  }

  float bb[4], wa0[4], wa1[4], wpv[4], gg[4], gb[4];
#pragma unroll
  for (int ni = 0; ni < 4; ++ni) {
    const int c = wave * 64 + ni * 16 + (lane & 15);
    bb[ni] = bias[c]; wa0[ni] = Wa[c]; wa1[ni] = Wa[256 + c];
    wpv[ni] = wp[c]; gg[ni] = g1[c]; gb[ni] = b1g[c];
  }
  float* red = (float*)lds;              // [5][4 waves][64 rows]
  float* muA = (float*)(lds + 5120);
  float* isA = (float*)(lds + 5376);
  const float inv = 1.f / 2048.f;
#pragma unroll
  for (int mi = 0; mi < 4; ++mi) {
#pragma unroll
    for (int reg = 0; reg < 4; ++reg) {
      const int lrow = mi * 16 + (lane >> 4) * 4 + reg;
      const int row = bm + lrow;
      float v[4];
      float p0 = 0.f, p1 = 0.f, p2 = 0.f, p3 = 0.f, p4 = 0.f;
#pragma unroll
      for (int ni = 0; ni < 4; ++ni) {
        float t = accH[mi][ni][reg] + accC[mi][ni][reg] * inv + bb[ni];
        t = fmaxf(t, 0.f);
        v[ni] = t;
        p0 += t; p1 += t * wa0[ni]; p2 += t * wa1[ni]; p3 += t * wpv[ni];
        p4 += t * t;
      }
      if (row < M) {
#pragma unroll
        for (int ni = 0; ni < 4; ++ni)
          C[(size_t)row * 256 + wave * 64 + ni * 16 + (lane & 15)] = v[ni];
      }
#pragma unroll
      for (int ni = 0; ni < 4; ++ni) accH[mi][ni][reg] = v[ni];
#pragma unroll
      for (int off = 1; off < 16; off <<= 1) {
        p0 += __shfl_xor(p0, off, 64);
        p1 += __shfl_xor(p1, off, 64);
        p2 += __shfl_xor(p2, off, 64);
        p3 += __shfl_xor(p3, off, 64);
        p4 += __shfl_xor(p4, off, 64);
      }
      if ((lane & 15) == 0) {
        red[(0 * 4 + wave) * 64 + lrow] = p0;
        red[(1 * 4 + wave) * 64 + lrow] = p1;
        red[(2 * 4 + wave) * 64 + lrow] = p2;
        red[(3 * 4 + wave) * 64 + lrow] = p3;
        red[(4 * 4 + wave) * 64 + lrow] = p4;
      }
    }
  }
  __syncthreads();
  if (tid < 64) {
    float s0 = 0.f, s1 = 0.f, s2 = 0.f, s3 = 0.f, s4 = 0.f;
#pragma unroll
    for (int w = 0; w < 4; ++w) {
      s0 += red[(0 * 4 + w) * 64 + tid];
      s1 += red[(1 * 4 + w) * 64 + tid];
      s2 += red[(2 * 4 + w) * 64 + tid];
      s3 += red[(3 * 4 + w) * 64 + tid];
      s4 += red[(4 * 4 + w) * 64 + tid];
    }
    const int row = bm + tid;
    if (row < M) {
      delta[row] = s0; adst[row] = s1; asrc[row] = s2; xwp[row] = s3;
    }
    float mu = s0 * (1.f / 256.f);
    muA[tid] = mu;
    isA[tid] = rsqrtf(s4 * (1.f / 256.f) - mu * mu + 1e-5f);
  }
  __syncthreads();
#pragma unroll
  for (int mi = 0; mi < 4; ++mi) {
#pragma unroll
    for (int reg = 0; reg < 4; ++reg) {
      const int lrow = mi * 16 + (lane >> 4) * 4 + reg;
      const int row = bm + lrow;
      if (row >= M) continue;
      const float mu = muA[lrow], is = isA[lrow];
#pragma unroll
      for (int ni = 0; ni < 4; ++ni) {
        const int col = wave * 64 + ni * 16 + (lane & 15);
        hn[(size_t)row * 256 + col] = f2bf((accH[mi][ni][reg] - mu) * is * gg[ni] + gb[ni]);
      }
    }
  }
}

// X [M][256] f32 -> Xh, Xl (f16, lo scaled 2048)
__global__ void xsplit_k(const float* __restrict__ X, _Float16* __restrict__ Xh,
                         _Float16* __restrict__ Xl, int total4) {
  int i = blockIdx.x * 256 + threadIdx.x;
  if (i >= total4) return;
  float4 x = reinterpret_cast<const float4*>(X)[i];
  half4 h, l;
  float xs[4] = {x.x, x.y, x.z, x.w};
#pragma unroll
  for (int j = 0; j < 4; ++j) {
    _Float16 hv = (_Float16)xs[j];
    h[j] = hv;
    l[j] = (_Float16)((xs[j] - (float)hv) * 2048.f);
  }
  reinterpret_cast<half4*>(Xh)[i] = h;
  reinterpret_cast<half4*>(Xl)[i] = l;
}

// ---------------- bf16 MFMA GEMM: Cb = epi(A @ Bt^T + bias) ------------------
// EPI: 1 bias->bf16, 2 bias+gelu(fast erf)->bf16.  BM=BN=128, BK=64, 4 waves.
template <int EPI>
__launch_bounds__(256)
__global__ void gemm_mfma(const ushort* __restrict__ A, const ushort* __restrict__ Bt,
                          const float* __restrict__ bias, ushort* __restrict__ Cb,
                          int M, int N, int K) {
  __shared__ ushort As[128 * 64];
  __shared__ ushort Bs[128 * 64];
  const int tid = threadIdx.x;
  const int wave = tid >> 6, lane = tid & 63;
  const int bm = blockIdx.x * 128, bn = blockIdx.y * 128;
  const int wm = (wave >> 1) * 64, wn = (wave & 1) * 64;
  const int srow = lane >> 3;
  const int scol = (((lane & 7) ^ srow) << 3);

  f32x4 acc[4][4];
#pragma unroll
  for (int i = 0; i < 4; ++i)
#pragma unroll
    for (int j = 0; j < 4; ++j) acc[i][j] = (f32x4){0.f, 0.f, 0.f, 0.f};

  for (int k0 = 0; k0 < K; k0 += 64) {
#pragma unroll
    for (int r = 0; r < 4; ++r) {
      const int ch = r * 4 + wave;
      int ar = bm + ch * 8 + srow;
      ar = (ar < M) ? ar : (M - 1);
      gload16(A + (size_t)ar * K + k0 + scol, (char*)As + ch * 1024);
      const int br = bn + ch * 8 + srow;
      gload16(Bt + (size_t)br * K + k0 + scol, (char*)Bs + ch * 1024);
    }
    __syncthreads();
#pragma unroll
    for (int kk = 0; kk < 2; ++kk) {
      const int c = (kk * 32 + (lane >> 4) * 8) * 2;
      short8 a[4];
#pragma unroll
      for (int mi = 0; mi < 4; ++mi) {
        const int rr = wm + mi * 16 + (lane & 15);
        a[mi] = *(const short8*)((const char*)As + rr * 128 + (c ^ ((rr & 7) << 4)));
      }
#pragma unroll
      for (int ni = 0; ni < 4; ++ni) {
        const int rr = wn + ni * 16 + (lane & 15);
        short8 b = *(const short8*)((const char*)Bs + rr * 128 + (c ^ ((rr & 7) << 4)));
#pragma unroll
        for (int mi = 0; mi < 4; ++mi)
          acc[mi][ni] = __builtin_amdgcn_mfma_f32_16x16x32_bf16(a[mi], b,
                                                                acc[mi][ni], 0, 0, 0);
      }
    }
    __syncthreads();
  }

  float bb[4];
#pragma unroll
  for (int ni = 0; ni < 4; ++ni) bb[ni] = bias[bn + wn + ni * 16 + (lane & 15)];
#pragma unroll
  for (int mi = 0; mi < 4; ++mi) {
#pragma unroll
    for (int reg = 0; reg < 4; ++reg) {
      const int row = bm + wm + mi * 16 + (lane >> 4) * 4 + reg;
      if (row >= M) continue;
#pragma unroll
      for (int ni = 0; ni < 4; ++ni) {
        const int col = bn + wn + ni * 16 + (lane & 15);
        float v = acc[mi][ni][reg] + bb[ni];
        if (EPI == 2) v = gelu_f(v);
        Cb[(size_t)row * N + col] = f2bf(v);
      }
    }
  }
}

// -------- fused FFN2 + residual + LN1_{l+1}: 8 waves, tile 128x256, K=512 ----
// LAST=0: h' = h + u@W2t^T + b2 (stored f32); hn = LN(h') bf16.
// LAST=1: hn = bf16(h') only.
template <int LAST>
__launch_bounds__(512, 4)
__global__ void gemm_ffn2ln(const ushort* __restrict__ A, const ushort* __restrict__ Bt,
                            const float* __restrict__ bias, const float* __restrict__ g1,
                            const float* __restrict__ b1g, float* __restrict__ h,
                            ushort* __restrict__ hn, int M) {
  __shared__ ushort As[128 * 64];   // 16 KB
  __shared__ ushort Bs[256 * 64];   // 32 KB
  const int tid = threadIdx.x;
  const int wave = tid >> 6, lane = tid & 63;
  const int bm = blockIdx.x * 128;
  const int wm = (wave >> 2) * 64, wn = (wave & 3) * 64;
  const int srow = lane >> 3;
  const int scol = (((lane & 7) ^ srow) << 3);

  f32x4 acc[4][4];
#pragma unroll
  for (int i = 0; i < 4; ++i)
#pragma unroll
    for (int j = 0; j < 4; ++j) acc[i][j] = (f32x4){0.f, 0.f, 0.f, 0.f};

  for (int k0 = 0; k0 < 512; k0 += 64) {
#pragma unroll
    for (int r = 0; r < 2; ++r) {
      const int ch = r * 8 + wave;
      int ar = bm + ch * 8 + srow;
      ar = (ar < M) ? ar : (M - 1);
      gload16(A + (size_t)ar * 512 + k0 + scol, (char*)As + ch * 1024);
    }
#pragma unroll
    for (int r = 0; r < 4; ++r) {
      const int ch = r * 8 + wave;
      const int br = ch * 8 + srow;
      gload16(Bt + (size_t)br * 512 + k0 + scol, (char*)Bs + ch * 1024);
    }
    __syncthreads();
#pragma unroll
    for (int kk = 0; kk < 2; ++kk) {
      const int c = (kk * 32 + (lane >> 4) * 8) * 2;
      short8 a[4];
#pragma unroll
      for (int mi = 0; mi < 4; ++mi) {
        const int rr = wm + mi * 16 + (lane & 15);
        a[mi] = *(const short8*)((const char*)As + rr * 128 + (c ^ ((rr & 7) << 4)));
      }
#pragma unroll
      for (int ni = 0; ni < 4; ++ni) {
        const int rr = wn + ni * 16 + (lane & 15);
        short8 b = *(const short8*)((const char*)Bs + rr * 128 + (c ^ ((rr & 7) << 4)));
#pragma unroll
        for (int mi = 0; mi < 4; ++mi)
          acc[mi][ni] = __builtin_amdgcn_mfma_f32_16x16x32_bf16(a[mi], b,
                                                                acc[mi][ni], 0, 0, 0);
      }
    }
    __syncthreads();
  }

  float bb[4];
#pragma unroll
  for (int ni = 0; ni < 4; ++ni) bb[ni] = bias[wn + ni * 16 + (lane & 15)];

  float* redS = (float*)As;            // [4 n-waves][128 rows]
  float* redQ = redS + 512;
  float* muA  = redQ + 512;            // [128]
  float* isA  = muA + 128;             // [128]

#pragma unroll
  for (int mi = 0; mi < 4; ++mi) {
#pragma unroll
    for (int reg = 0; reg < 4; ++reg) {
      const int lrow = wm + mi * 16 + (lane >> 4) * 4 + reg;
      const int row = bm + lrow;
      const bool ok = (row < M);
      float pS = 0.f, pQ = 0.f;
#pragma unroll
      for (int ni = 0; ni < 4; ++ni) {
        const int col = wn + ni * 16 + (lane & 15);
        float t = acc[mi][ni][reg] + bb[ni];
        if (ok) t += h[(size_t)row * 256 + col];
        acc[mi][ni][reg] = t;
        if (LAST) {
          if (ok) hn[(size_t)row * 256 + col] = f2bf(t);
        } else {
          if (ok) h[(size_t)row * 256 + col] = t;
          pS += t;
          pQ += t * t;
        }
      }
      if (!LAST) {
#pragma unroll
        for (int off = 1; off < 16; off <<= 1) {
          pS += __shfl_xor(pS, off, 64);
          pQ += __shfl_xor(pQ, off, 64);
        }
        if ((lane & 15) == 0) {
          redS[(wave & 3) * 128 + lrow] = pS;
          redQ[(wave & 3) * 128 + lrow] = pQ;
        }
      }
    }
  }
  if (LAST) return;
  __syncthreads();
  if (tid < 128) {
    float S = redS[tid] + redS[128 + tid] + redS[256 + tid] + redS[384 + tid];
    float Q = redQ[tid] + redQ[128 + tid] + redQ[256 + tid] + redQ[384 + tid];
    float mu = S * (1.f / 256.f);
    muA[tid] = mu;
    isA[tid] = rsqrtf(Q * (1.f / 256.f) - mu * mu + 1e-5f);
  }
  __syncthreads();
  float gg[4], gb[4];
#pragma unroll
  for (int ni = 0; ni < 4; ++ni) {
    gg[ni] = g1[wn + ni * 16 + (lane & 15)];
    gb[ni] = b1g[wn + ni * 16 + (lane & 15)];
  }
#pragma unroll
  for (int mi = 0; mi < 4; ++mi) {
#pragma unroll
    for (int reg = 0; reg < 4; ++reg) {
      const int lrow = wm + mi * 16 + (lane >> 4) * 4 + reg;
      const int row = bm + lrow;
      if (row >= M) continue;
      const float mu = muA[lrow], is = isA[lrow];
#pragma unroll
      for (int ni = 0; ni < 4; ++ni) {
        const int col = wn + ni * 16 + (lane & 15);
        hn[(size_t)row * 256 + col] = f2bf((acc[mi][ni][reg] - mu) * is * gg[ni] + gb[ni]);
      }
    }
  }
}

// ---------------- bf16 MFMA output GEMM: C(f32) = A @ Bt^T + bias ------------
__launch_bounds__(256)
__global__ void gemm_out(const ushort* __restrict__ A, const ushort* __restrict__ Bt,
                         const float* __restrict__ bias, float* __restrict__ C, int M) {
  __shared__ ushort As[128 * 64];
  __shared__ ushort Bs[64 * 64];
  const int tid = threadIdx.x;
  const int wave = tid >> 6, lane = tid & 63;
  const int bm = blockIdx.x * 128;
  const int wm = wave * 32;
  const int srow = lane >> 3;
  const int scol = (((lane & 7) ^ srow) << 3);
  f32x4 acc[2][4];
#pragma unroll
  for (int i = 0; i < 2; ++i)
#pragma unroll
    for (int j = 0; j < 4; ++j) acc[i][j] = (f32x4){0.f, 0.f, 0.f, 0.f};

  for (int k0 = 0; k0 < 256; k0 += 64) {
#pragma unroll
    for (int r = 0; r < 4; ++r) {
      const int ch = r * 4 + wave;
      int ar = bm + ch * 8 + srow;
      ar = (ar < M) ? ar : (M - 1);
      gload16(A + (size_t)ar * 256 + k0 + scol, (char*)As + ch * 1024);
    }
#pragma unroll
    for (int r = 0; r < 2; ++r) {
      const int ch = r * 4 + wave;
      const int br = ch * 8 + srow;
      gload16(Bt + (size_t)br * 256 + k0 + scol, (char*)Bs + ch * 1024);
    }
    __syncthreads();
#pragma unroll
    for (int kk = 0; kk < 2; ++kk) {
      const int c = (kk * 32 + (lane >> 4) * 8) * 2;
      short8 a[2], b[4];
#pragma unroll
      for (int mi = 0; mi < 2; ++mi) {
        const int rr = wm + mi * 16 + (lane & 15);
        a[mi] = *(const short8*)((const char*)As + rr * 128 + (c ^ ((rr & 7) << 4)));
      }
#pragma unroll
      for (int ni = 0; ni < 4; ++ni) {
        const int rr = ni * 16 + (lane & 15);
        b[ni] = *(const short8*)((const char*)Bs + rr * 128 + (c ^ ((rr & 7) << 4)));
      }
#pragma unroll
      for (int mi = 0; mi < 2; ++mi)
#pragma unroll
        for (int ni = 0; ni < 4; ++ni)
          acc[mi][ni] = __builtin_amdgcn_mfma_f32_16x16x32_bf16(a[mi], b[ni],
                                                                acc[mi][ni], 0, 0, 0);
    }
    __syncthreads();
  }
  float bb[4];
#pragma unroll
  for (int ni = 0; ni < 4; ++ni) bb[ni] = bias[ni * 16 + (lane & 15)];
#pragma unroll
  for (int mi = 0; mi < 2; ++mi) {
#pragma unroll
    for (int reg = 0; reg < 4; ++reg) {
      const int row = bm + wm + mi * 16 + (lane >> 4) * 4 + reg;
      if (row >= M) continue;
#pragma unroll
      for (int ni = 0; ni < 4; ++ni) {
        const int col = ni * 16 + (lane & 15);
        C[(size_t)row * 64 + col] = acc[mi][ni][reg] + bb[ni];
      }
    }
  }
}

// ---- one-shot prep: weight transposes/converts (incl. Wi f16 split) + zero --
#define W_IN 65536
#define W_TOTAL (196608 + 393216 + 393216 + 16384)
__global__ void prep_k(const float* __restrict__ Wi, const float* __restrict__ Wc,
                       const float* __restrict__ W1, const float* __restrict__ W2,
                       const float* __restrict__ Wo, _Float16* __restrict__ WiTh,
                       _Float16* __restrict__ WiTl, ushort* __restrict__ WcT,
                       ushort* __restrict__ W1T, ushort* __restrict__ W2T,
                       ushort* __restrict__ WoT, float* __restrict__ zbase, int zn) {
  int i = blockIdx.x * 256 + threadIdx.x;
  if (i < W_IN) {
    int n = i >> 8, k = i & 255;
    float w = Wi[(size_t)k * 256 + n];
    _Float16 hv = (_Float16)w;
    WiTh[i] = hv;
    WiTl[i] = (_Float16)((w - (float)hv) * 2048.f);
  } else if ((i -= W_IN) < W_TOTAL) {
    int j = i;
    if (j < 196608) {
      int l = j / 65536, r = j % 65536, n = r >> 8, k = r & 255;
      WcT[j] = f2bf(Wc[(size_t)l * 65536 + k * 256 + n]);
    } else if ((j -= 196608) < 393216) {
      int l = j / 131072, r = j % 131072, n = r >> 8, k = r & 255;
      W1T[j] = f2bf(W1[(size_t)l * 131072 + k * 512 + n]);
    } else if ((j -= 393216) < 393216) {
      int l = j / 131072, r = j % 131072, n = r >> 9, k = r & 511;
      W2T[j] = f2bf(W2[(size_t)l * 131072 + k * 256 + n]);
    } else {
      j -= 393216;
      int n = j >> 8, k = j & 255;
      WoT[j] = f2bf(Wo[k * 64 + n]);
    }
  } else {
    int z = i - W_TOTAL;
    if (z < zn) zbase[z] = 0.f;
  }
}

__global__ void neigh_k(const int* __restrict__ src, const int* __restrict__ dst,
                        const float* __restrict__ delta, float* __restrict__ neigh, int E) {
  int e = blockIdx.x * 256 + threadIdx.x;
  if (e < E) atomicAdd(&neigh[dst[e]], delta[src[e]]);
}

// edge logits (pi inline); slots layout [t][N]
__global__ void logits_k(const int* __restrict__ src, const int* __restrict__ dst,
                         const float* __restrict__ adst, const float* __restrict__ asrc,
                         const float* __restrict__ xwp, const float* __restrict__ neigh,
                         const float* __restrict__ Wa, const float* __restrict__ ba,
                         float* __restrict__ expe, float* __restrict__ denom,
                         int* __restrict__ cnt, int* __restrict__ slots,
                         int E, int Et, int N) {
  int e = blockIdx.x * 256 + threadIdx.x;
  if (e >= Et) return;
  int s, d;
  if (e < E) { s = src[e]; d = dst[e]; } else { s = e - E; d = s; }
  float pis = 1.f / (1.f + expf(-(xwp[s] + neigh[s])));
  float v = adst[d] + asrc[s] + pis * Wa[512] + ba[0];
  v = (v >= 0.f ? v : 0.2f * v) / TAUF;
  v = fminf(fmaxf(v, -5.f), 5.f);
  float ex = expf(v);
  expe[e] = ex;
  atomicAdd(&denom[d], ex);
  int p = atomicAdd(&cnt[d], 1);
  if (p < 64) slots[(size_t)p * N + d] = e;
}

__device__ __forceinline__ bool better(float a, int e, float a2, int e2) {
  return a > a2 || (a == a2 && e < e2);
}

__global__ void topk_k(const int* __restrict__ cnt, const int* __restrict__ slots,
                       const float* __restrict__ expe, const float* __restrict__ denom,
                       const int* __restrict__ src, int* __restrict__ kcnt,
                       int* __restrict__ ksrc, float* __restrict__ kw, int N, int E) {
  int d = blockIdx.x * 256 + threadIdx.x;
  if (d >= N) return;
  int deg = min(cnt[d], 64);
  float D = denom[d] + 1e-16f;
  float av[8]; int ai[8]; int kc = 0;
  for (int t = 0; t < deg; ++t) {
    int e = slots[(size_t)t * N + d];
    float a = expe[e] / D;
    if (kc < 8) {
      int p = kc++;
      while (p > 0 && better(a, e, av[p - 1], ai[p - 1])) {
        av[p] = av[p - 1]; ai[p] = ai[p - 1]; --p;
      }
      av[p] = a; ai[p] = e;
    } else if (better(a, e, av[7], ai[7])) {
      int p = 7;
      while (p > 0 && better(a, e, av[p - 1], ai[p - 1])) {
        av[p] = av[p - 1]; ai[p] = ai[p - 1]; --p;
      }
      av[p] = a; ai[p] = e;
    }
  }
  float ks = 0.f;
  for (int j = 0; j < kc; ++j) ks += av[j];
  kcnt[d] = kc;
  for (int j = 0; j < kc; ++j) {
    int e = ai[j];
    ksrc[(size_t)d * 8 + j] = (e < E) ? src[e] : (e - E);
    kw[(size_t)d * 8 + j] = av[j] / (ks + 1e-16f);
  }
}

// fused: h += relu(sum_j kw*xp[ksrc]); then LN2 -> hn (bf16). One wave per row.
__global__ void agg_ln_k(const ushort* __restrict__ xp, const int* __restrict__ kcnt,
                         const int* __restrict__ ksrc, const float* __restrict__ kw,
                         const float* __restrict__ g, const float* __restrict__ b,
                         float* __restrict__ h, ushort* __restrict__ hn, int N) {
  int d = blockIdx.x * 4 + (threadIdx.x >> 6);
  if (d >= N) return;
  int lane = threadIdx.x & 63;
  int kc = kcnt[d];
  float a0 = 0.f, a1 = 0.f, a2 = 0.f, a3 = 0.f;
  for (int j = 0; j < kc; ++j) {
    int s = ksrc[(size_t)d * 8 + j];
    float w = kw[(size_t)d * 8 + j];
    us4 xv = *reinterpret_cast<const us4*>(xp + (size_t)s * 256 + lane * 4);
    a0 += w * bf2f(xv.x);
    a1 += w * bf2f(xv.y);
    a2 += w * bf2f(xv.z);
    a3 += w * bf2f(xv.w);
  }
  float* hr = h + (size_t)d * 256 + lane * 4;
  float4 hv = *reinterpret_cast<const float4*>(hr);
  float v0 = hv.x + fmaxf(a0, 0.f);
  float v1 = hv.y + fmaxf(a1, 0.f);
  float v2 = hv.z + fmaxf(a2, 0.f);
  float v3 = hv.w + fmaxf(a3, 0.f);
  *reinterpret_cast<float4*>(hr) = make_float4(v0, v1, v2, v3);
  float s = wave_sum(v0 + v1 + v2 + v3);
  float mu = s * (1.f / 256.f);
  float q = (v0 - mu) * (v0 - mu) + (v1 - mu) * (v1 - mu) +
            (v2 - mu) * (v2 - mu) + (v3 - mu) * (v3 - mu);
  q = wave_sum(q);
  float is = rsqrtf(q * (1.f / 256.f) + 1e-5f);
  float4 gg = *reinterpret_cast<const float4*>(g + lane * 4);
  float4 bb = *reinterpret_cast<const float4*>(b + lane * 4);
  us4 out;
  out.x = f2bf((v0 - mu) * is * gg.x + bb.x);
  out.y = f2bf((v1 - mu) * is * gg.y + bb.y);
  out.z = f2bf((v2 - mu) * is * gg.z + bb.z);
  out.w = f2bf((v3 - mu) * is * gg.w + bb.w);
  *reinterpret_cast<us4*>(hn + (size_t)d * 256 + lane * 4) = out;
}

extern "C" void kernel_launch(void* const* d_in, const int* in_sizes, int n_in,
                              void* d_out, int out_size, void* d_ws, size_t ws_size,
                              hipStream_t stream) {
  const float* X   = (const float*)d_in[0];
  const int*   EI  = (const int*)d_in[1];
  const float* Wi  = (const float*)d_in[2];
  const float* bi  = (const float*)d_in[3];
  const float* wp  = (const float*)d_in[4];
  const float* Wa  = (const float*)d_in[5];
  const float* ba  = (const float*)d_in[6];
  const float* l1g = (const float*)d_in[7];
  const float* l1b = (const float*)d_in[8];
  const float* l2g = (const float*)d_in[9];
  const float* l2b = (const float*)d_in[10];
  const float* W1  = (const float*)d_in[11];
  const float* b1  = (const float*)d_in[12];
  const float* W2  = (const float*)d_in[13];
  const float* b2  = (const float*)d_in[14];
  const float* Wc  = (const float*)d_in[15];
  const float* bc  = (const float*)d_in[16];
  const float* Wo  = (const float*)d_in[17];
  const float* bo  = (const float*)d_in[18];

  const int N = in_sizes[0] / 256;
  const int E = in_sizes[1] / 2;
  const int Et = E + N;
  const int* srcp = EI;
  const int* dstp = EI + E;

  float* ws = (float*)d_ws;
  size_t off = 0;
  auto alloc = [&](size_t n) { float* p = ws + off; off += n; return p; };
  const size_t NH = (size_t)N * 256;
  float*  h    = alloc(NH);                            // f32 [N][256]
  ushort* hn   = (ushort*)alloc(NH / 2);               // bf16 [N][256]
  ushort* xp   = (ushort*)alloc(NH / 2);               // bf16 [N][256]
  float*  ualias = alloc(NH);                          // u (bf16 [N][512]) / Xh+Xl
  ushort* u    = (ushort*)ualias;
  _Float16* Xh = (_Float16*)ualias;
  _Float16* Xl = Xh + NH;
  _Float16* WiTh = (_Float16*)alloc(65536 / 2);
  _Float16* WiTl = (_Float16*)alloc(65536 / 2);
  ushort* WcT  = (ushort*)alloc(3 * 65536 / 2);
  ushort* W1T  = (ushort*)alloc(3 * 131072 / 2);
  ushort* W2T  = (ushort*)alloc(3 * 131072 / 2);
  ushort* WoT  = (ushort*)alloc(16384 / 2);
  float* delta = alloc(N);
  float* adst  = alloc(N);
  float* asrc  = alloc(N);
  float* xwp   = alloc(N);
  float* expe  = alloc(Et);
  float* neigh = alloc(N);       // ┐ contiguous zero region (3N)
  float* denom = alloc(N);       // │
  int*   cnt   = (int*)alloc(N); // ┘
  int*   slots = (int*)alloc((size_t)N * 64);
  int*   kcnt  = (int*)alloc(N);
  int*   ksrc  = (int*)alloc((size_t)N * 8);
  float* kw    = alloc((size_t)N * 8);

  prep_k<<<(W_IN + W_TOTAL + 3 * N + 255) / 256, 256, 0, stream>>>(
      Wi, Wc, W1, W2, Wo, WiTh, WiTl, WcT, W1T, W2T, WoT, neigh, 3 * N);
  xsplit_k<<<((int)(NH / 4) + 255) / 256, 256, 0, stream>>>(X, Xh, Xl, (int)(NH / 4));

  gemm_in_mfma<<<(N + 63) / 64, 256, 0, stream>>>(
      Xh, Xl, WiTh, WiTl, bi, Wa, wp, l1g, l1b, h, hn,
      delta, adst, asrc, xwp, N);
  neigh_k<<<(E + 255) / 256, 256, 0, stream>>>(srcp, dstp, delta, neigh, E);
  logits_k<<<(Et + 255) / 256, 256, 0, stream>>>(srcp, dstp, adst, asrc, xwp, neigh,
                                                 Wa, ba, expe, denom, cnt, slots,
                                                 E, Et, N);
  topk_k<<<(N + 255) / 256, 256, 0, stream>>>(cnt, slots, expe, denom, srcp,
                                              kcnt, ksrc, kw, N, E);

  const int GM = (N + 127) / 128;
  for (int l = 0; l < 3; ++l) {
    gemm_mfma<1><<<dim3(GM, 2), 256, 0, stream>>>(
        hn, WcT + (size_t)l * 65536, bc + l * 256, xp, N, 256, 256);
    agg_ln_k<<<(N + 3) / 4, 256, 0, stream>>>(xp, kcnt, ksrc, kw,
                                              l2g + l * 256, l2b + l * 256, h, hn, N);
    gemm_mfma<2><<<dim3(GM, 4), 256, 0, stream>>>(
        hn, W1T + (size_t)l * 131072, b1 + l * 512, u, N, 512, 256);
    if (l < 2)
      gemm_ffn2ln<0><<<GM, 512, 0, stream>>>(
          u, W2T + (size_t)l * 131072, b2 + l * 256,
          l1g + (l + 1) * 256, l1b + (l + 1) * 256, h, hn, N);
    else
      gemm_ffn2ln<1><<<GM, 512, 0, stream>>>(
          u, W2T + (size_t)l * 131072, b2 + l * 256,
          nullptr, nullptr, h, hn, N);
  }
  gemm_out<<<(N + 127) / 128, 256, 0, stream>>>(hn, WoT, bo, (float*)d_out, N);
}

// Round 7
// 646.316 us; speedup vs baseline: 1.3819x; 1.0472x over previous
//
#include <hip/hip_runtime.h>
#include <math.h>

#define TAUF 0.9f

typedef unsigned int u32;
typedef unsigned short ushort;
typedef __attribute__((ext_vector_type(8))) short short8;
typedef __attribute__((ext_vector_type(8))) _Float16 half8;
typedef __attribute__((ext_vector_type(4))) _Float16 half4;
typedef __attribute__((ext_vector_type(4))) float f32x4;
typedef __attribute__((ext_vector_type(4))) unsigned short us4;

__device__ __forceinline__ ushort f2bf(float f) {
  u32 u = __builtin_bit_cast(u32, f);
  u32 r = (u + 0x7FFFu + ((u >> 16) & 1u)) >> 16;
  return (ushort)r;
}
__device__ __forceinline__ float bf2f(ushort s) {
  u32 u = ((u32)s) << 16;
  return __builtin_bit_cast(float, u);
}

// exact-form GELU via A&S 7.1.26 erf approx (|erf err| < 1.5e-7)
__device__ __forceinline__ float gelu_f(float x) {
  float z = x * 0.70710678118654752f;
  float az = fabsf(z);
  float t = 1.f / fmaf(0.3275911f, az, 1.f);
  float poly = t * fmaf(t, fmaf(t, fmaf(t, fmaf(t, 1.061405429f, -1.453152027f),
                                        1.421413741f), -0.284496736f), 0.254829592f);
  float erfa = fmaf(-poly, __expf(-az * az), 1.f);
  float s = (z < 0.f) ? -erfa : erfa;
  return 0.5f * x * (1.f + s);
}

__device__ __forceinline__ void gload16(const void* g, void* l) {
  __builtin_amdgcn_global_load_lds(
      (const __attribute__((address_space(1))) u32*)g,
      (__attribute__((address_space(3))) u32*)l, 16, 0, 0);
}

// ---------- split-f16 input GEMM: h = relu(X @ Wi + bi), exact to ~f32 -------
__launch_bounds__(256, 2)
__global__ void gemm_in_mfma(const _Float16* __restrict__ Ah, const _Float16* __restrict__ Al,
                             const _Float16* __restrict__ Bh, const _Float16* __restrict__ Bl,
                             const float* __restrict__ bias, const float* __restrict__ Wa,
                             const float* __restrict__ wp, const float* __restrict__ g1,
                             const float* __restrict__ b1g, float* __restrict__ C,
                             ushort* __restrict__ hn, float* __restrict__ delta,
                             float* __restrict__ adst, float* __restrict__ asrc,
                             float* __restrict__ xwp, int M) {
  __shared__ char lds[81920];  // Ah 8K | Al 8K | Bh 32K | Bl 32K
  char* As_h = lds;
  char* As_l = lds + 8192;
  char* Bs_h = lds + 16384;
  char* Bs_l = lds + 49152;
  const int tid = threadIdx.x;
  const int wave = tid >> 6, lane = tid & 63;
  const int bm = blockIdx.x * 64;
  const int srow = lane >> 3;
  const int scol = (((lane & 7) ^ srow) << 3);

  f32x4 accH[4][4], accC[4][4];
#pragma unroll
  for (int i = 0; i < 4; ++i)
#pragma unroll
    for (int j = 0; j < 4; ++j) {
      accH[i][j] = (f32x4){0.f, 0.f, 0.f, 0.f};
      accC[i][j] = (f32x4){0.f, 0.f, 0.f, 0.f};
    }

  for (int k0 = 0; k0 < 256; k0 += 64) {
#pragma unroll
    for (int r = 0; r < 2; ++r) {
      const int ch = r * 4 + wave;
      int ar = bm + ch * 8 + srow;
      ar = (ar < M) ? ar : (M - 1);
      gload16(Ah + (size_t)ar * 256 + k0 + scol, As_h + ch * 1024);
      gload16(Al + (size_t)ar * 256 + k0 + scol, As_l + ch * 1024);
    }
#pragma unroll
    for (int r = 0; r < 8; ++r) {
      const int ch = r * 4 + wave;
      const int br = ch * 8 + srow;
      gload16(Bh + (size_t)br * 256 + k0 + scol, Bs_h + ch * 1024);
      gload16(Bl + (size_t)br * 256 + k0 + scol, Bs_l + ch * 1024);
    }
    __syncthreads();
#pragma unroll
    for (int kk = 0; kk < 2; ++kk) {
      const int c = (kk * 32 + (lane >> 4) * 8) * 2;
      half8 ah[4], bh[4];
#pragma unroll
      for (int mi = 0; mi < 4; ++mi) {
        const int rr = mi * 16 + (lane & 15);
        ah[mi] = *(const half8*)(As_h + rr * 128 + (c ^ ((rr & 7) << 4)));
      }
#pragma unroll
      for (int ni = 0; ni < 4; ++ni) {
        const int rr = wave * 64 + ni * 16 + (lane & 15);
        bh[ni] = *(const half8*)(Bs_h + rr * 128 + (c ^ ((rr & 7) << 4)));
      }
#pragma unroll
      for (int mi = 0; mi < 4; ++mi)
#pragma unroll
        for (int ni = 0; ni < 4; ++ni)
          accH[mi][ni] = __builtin_amdgcn_mfma_f32_16x16x32_f16(ah[mi], bh[ni],
                                                                accH[mi][ni], 0, 0, 0);
      half8 al[4];
#pragma unroll
      for (int mi = 0; mi < 4; ++mi) {
        const int rr = mi * 16 + (lane & 15);
        al[mi] = *(const half8*)(As_l + rr * 128 + (c ^ ((rr & 7) << 4)));
      }
#pragma unroll
      for (int mi = 0; mi < 4; ++mi)
#pragma unroll
        for (int ni = 0; ni < 4; ++ni)
          accC[mi][ni] = __builtin_amdgcn_mfma_f32_16x16x32_f16(al[mi], bh[ni],
                                                                accC[mi][ni], 0, 0, 0);
      half8 bl[4];
#pragma unroll
      for (int ni = 0; ni < 4; ++ni) {
        const int rr = wave * 64 + ni * 16 + (lane & 15);
        bl[ni] = *(const half8*)(Bs_l + rr * 128 + (c ^ ((rr & 7) << 4)));
      }
#pragma unroll
      for (int mi = 0; mi < 4; ++mi)
#pragma unroll
        for (int ni = 0; ni < 4; ++ni)
          accC[mi][ni] = __builtin_amdgcn_mfma_f32_16x16x32_f16(ah[mi], bl[ni],
                                                                accC[mi][ni], 0, 0, 0);
    }
    __syncthreads();
  }

  float bb[4], wa0[4], wa1[4], wpv[4], gg[4], gb[4];
#pragma unroll
  for (int ni = 0; ni < 4; ++ni) {
    const int c = wave * 64 + ni * 16 + (lane & 15);
    bb[ni] = bias[c]; wa0[ni] = Wa[c]; wa1[ni] = Wa[256 + c];
    wpv[ni] = wp[c]; gg[ni] = g1[c]; gb[ni] = b1g[c];
  }
  float* red = (float*)lds;              // [5][4 waves][64 rows]
  float* muA = (float*)(lds + 5120);
  float* isA = (float*)(lds + 5376);
  const float inv = 1.f / 2048.f;
#pragma unroll
  for (int mi = 0; mi < 4; ++mi) {
#pragma unroll
    for (int reg = 0; reg < 4; ++reg) {
      const int lrow = mi * 16 + (lane >> 4) * 4 + reg;
      const int row = bm + lrow;
      float v[4];
      float p0 = 0.f, p1 = 0.f, p2 = 0.f, p3 = 0.f, p4 = 0.f;
#pragma unroll
      for (int ni = 0; ni < 4; ++ni) {
        float t = accH[mi][ni][reg] + accC[mi][ni][reg] * inv + bb[ni];
        t = fmaxf(t, 0.f);
        v[ni] = t;
        p0 += t; p1 += t * wa0[ni]; p2 += t * wa1[ni]; p3 += t * wpv[ni];
        p4 += t * t;
      }
      if (row < M) {
#pragma unroll
        for (int ni = 0; ni < 4; ++ni)
          C[(size_t)row * 256 + wave * 64 + ni * 16 + (lane & 15)] = v[ni];
      }
#pragma unroll
      for (int ni = 0; ni < 4; ++ni) accH[mi][ni][reg] = v[ni];
#pragma unroll
      for (int off = 1; off < 16; off <<= 1) {
        p0 += __shfl_xor(p0, off, 64);
        p1 += __shfl_xor(p1, off, 64);
        p2 += __shfl_xor(p2, off, 64);
        p3 += __shfl_xor(p3, off, 64);
        p4 += __shfl_xor(p4, off, 64);
      }
      if ((lane & 15) == 0) {
        red[(0 * 4 + wave) * 64 + lrow] = p0;
        red[(1 * 4 + wave) * 64 + lrow] = p1;
        red[(2 * 4 + wave) * 64 + lrow] = p2;
        red[(3 * 4 + wave) * 64 + lrow] = p3;
        red[(4 * 4 + wave) * 64 + lrow] = p4;
      }
    }
  }
  __syncthreads();
  if (tid < 64) {
    float s0 = 0.f, s1 = 0.f, s2 = 0.f, s3 = 0.f, s4 = 0.f;
#pragma unroll
    for (int w = 0; w < 4; ++w) {
      s0 += red[(0 * 4 + w) * 64 + tid];
      s1 += red[(1 * 4 + w) * 64 + tid];
      s2 += red[(2 * 4 + w) * 64 + tid];
      s3 += red[(3 * 4 + w) * 64 + tid];
      s4 += red[(4 * 4 + w) * 64 + tid];
    }
    const int row = bm + tid;
    if (row < M) {
      delta[row] = s0; adst[row] = s1; asrc[row] = s2; xwp[row] = s3;
    }
    float mu = s0 * (1.f / 256.f);
    muA[tid] = mu;
    isA[tid] = rsqrtf(s4 * (1.f / 256.f) - mu * mu + 1e-5f);
  }
  __syncthreads();
#pragma unroll
  for (int mi = 0; mi < 4; ++mi) {
#pragma unroll
    for (int reg = 0; reg < 4; ++reg) {
      const int lrow = mi * 16 + (lane >> 4) * 4 + reg;
      const int row = bm + lrow;
      if (row >= M) continue;
      const float mu = muA[lrow], is = isA[lrow];
#pragma unroll
      for (int ni = 0; ni < 4; ++ni) {
        const int col = wave * 64 + ni * 16 + (lane & 15);
        hn[(size_t)row * 256 + col] = f2bf((accH[mi][ni][reg] - mu) * is * gg[ni] + gb[ni]);
      }
    }
  }
}

// X [M][256] f32 -> Xh, Xl (f16, lo scaled 2048)
__global__ void xsplit_k(const float* __restrict__ X, _Float16* __restrict__ Xh,
                         _Float16* __restrict__ Xl, int total4) {
  int i = blockIdx.x * 256 + threadIdx.x;
  if (i >= total4) return;
  float4 x = reinterpret_cast<const float4*>(X)[i];
  half4 h, l;
  float xs[4] = {x.x, x.y, x.z, x.w};
#pragma unroll
  for (int j = 0; j < 4; ++j) {
    _Float16 hv = (_Float16)xs[j];
    h[j] = hv;
    l[j] = (_Float16)((xs[j] - (float)hv) * 2048.f);
  }
  reinterpret_cast<half4*>(Xh)[i] = h;
  reinterpret_cast<half4*>(Xl)[i] = l;
}

// -------- gather-average: hagg[d] = sum_j kw[d][j] * hn[ksrc[d][j]] ----------
// ksrc/kw padded to 8 (w=0) by topk_k; 8 loads issued together for ILP.
__global__ void gather_k(const ushort* __restrict__ hn, const int* __restrict__ ksrc,
                         const float* __restrict__ kw, ushort* __restrict__ hagg, int N) {
  int d = blockIdx.x * 4 + (threadIdx.x >> 6);
  if (d >= N) return;
  int lane = threadIdx.x & 63;
  us4 xv[8];
  float w[8];
#pragma unroll
  for (int j = 0; j < 8; ++j) {
    int s = ksrc[(size_t)d * 8 + j];
    w[j] = kw[(size_t)d * 8 + j];
    xv[j] = *reinterpret_cast<const us4*>(hn + (size_t)s * 256 + lane * 4);
  }
  float a0 = 0.f, a1 = 0.f, a2 = 0.f, a3 = 0.f;
#pragma unroll
  for (int j = 0; j < 8; ++j) {
    a0 += w[j] * bf2f(xv[j].x);
    a1 += w[j] * bf2f(xv[j].y);
    a2 += w[j] * bf2f(xv[j].z);
    a3 += w[j] * bf2f(xv[j].w);
  }
  us4 o;
  o.x = f2bf(a0); o.y = f2bf(a1); o.z = f2bf(a2); o.w = f2bf(a3);
  *reinterpret_cast<us4*>(hagg + (size_t)d * 256 + lane * 4) = o;
}

// ---- conv + agg + residual + LN2, fused: 8 waves, BM=128, BN=256, K=256 -----
// t = relu(hagg @ WcT^T + bc) + h;  h = t (f32);  hn = LN2(t) (bf16).
__launch_bounds__(512, 4)
__global__ void gemm_conv_aggln(const ushort* __restrict__ A, const ushort* __restrict__ Bt,
                                const float* __restrict__ bias, const float* __restrict__ g2,
                                const float* __restrict__ b2g, float* __restrict__ h,
                                ushort* __restrict__ hn, int M) {
  __shared__ ushort As[128 * 64];   // 16 KB
  __shared__ ushort Bs[256 * 64];   // 32 KB
  const int tid = threadIdx.x;
  const int wave = tid >> 6, lane = tid & 63;
  const int bm = blockIdx.x * 128;
  const int wm = (wave >> 2) * 64, wn = (wave & 3) * 64;
  const int srow = lane >> 3;
  const int scol = (((lane & 7) ^ srow) << 3);

  f32x4 acc[4][4];
#pragma unroll
  for (int i = 0; i < 4; ++i)
#pragma unroll
    for (int j = 0; j < 4; ++j) acc[i][j] = (f32x4){0.f, 0.f, 0.f, 0.f};

  for (int k0 = 0; k0 < 256; k0 += 64) {
#pragma unroll
    for (int r = 0; r < 2; ++r) {
      const int ch = r * 8 + wave;
      int ar = bm + ch * 8 + srow;
      ar = (ar < M) ? ar : (M - 1);
      gload16(A + (size_t)ar * 256 + k0 + scol, (char*)As + ch * 1024);
    }
#pragma unroll
    for (int r = 0; r < 4; ++r) {
      const int ch = r * 8 + wave;
      const int br = ch * 8 + srow;
      gload16(Bt + (size_t)br * 256 + k0 + scol, (char*)Bs + ch * 1024);
    }
    __syncthreads();
#pragma unroll
    for (int kk = 0; kk < 2; ++kk) {
      const int c = (kk * 32 + (lane >> 4) * 8) * 2;
      short8 a[4];
#pragma unroll
      for (int mi = 0; mi < 4; ++mi) {
        const int rr = wm + mi * 16 + (lane & 15);
        a[mi] = *(const short8*)((const char*)As + rr * 128 + (c ^ ((rr & 7) << 4)));
      }
#pragma unroll
      for (int ni = 0; ni < 4; ++ni) {
        const int rr = wn + ni * 16 + (lane & 15);
        short8 b = *(const short8*)((const char*)Bs + rr * 128 + (c ^ ((rr & 7) << 4)));
#pragma unroll
        for (int mi = 0; mi < 4; ++mi)
          acc[mi][ni] = __builtin_amdgcn_mfma_f32_16x16x32_bf16(a[mi], b,
                                                                acc[mi][ni], 0, 0, 0);
      }
    }
    __syncthreads();
  }

  float bb[4];
#pragma unroll
  for (int ni = 0; ni < 4; ++ni) bb[ni] = bias[wn + ni * 16 + (lane & 15)];

  float* redS = (float*)As;            // [4 n-waves][128 rows]
  float* redQ = redS + 512;
  float* muA  = redQ + 512;            // [128]
  float* isA  = muA + 128;             // [128]

#pragma unroll
  for (int mi = 0; mi < 4; ++mi) {
#pragma unroll
    for (int reg = 0; reg < 4; ++reg) {
      const int lrow = wm + mi * 16 + (lane >> 4) * 4 + reg;
      const int row = bm + lrow;
      const bool ok = (row < M);
      float pS = 0.f, pQ = 0.f;
#pragma unroll
      for (int ni = 0; ni < 4; ++ni) {
        const int col = wn + ni * 16 + (lane & 15);
        float t = fmaxf(acc[mi][ni][reg] + bb[ni], 0.f);
        if (ok) {
          t += h[(size_t)row * 256 + col];
          h[(size_t)row * 256 + col] = t;
        }
        acc[mi][ni][reg] = t;
        pS += t;
        pQ += t * t;
      }
#pragma unroll
      for (int off = 1; off < 16; off <<= 1) {
        pS += __shfl_xor(pS, off, 64);
        pQ += __shfl_xor(pQ, off, 64);
      }
      if ((lane & 15) == 0) {
        redS[(wave & 3) * 128 + lrow] = pS;
        redQ[(wave & 3) * 128 + lrow] = pQ;
      }
    }
  }
  __syncthreads();
  if (tid < 128) {
    float S = redS[tid] + redS[128 + tid] + redS[256 + tid] + redS[384 + tid];
    float Q = redQ[tid] + redQ[128 + tid] + redQ[256 + tid] + redQ[384 + tid];
    float mu = S * (1.f / 256.f);
    muA[tid] = mu;
    isA[tid] = rsqrtf(Q * (1.f / 256.f) - mu * mu + 1e-5f);
  }
  __syncthreads();
  float gg[4], gb[4];
#pragma unroll
  for (int ni = 0; ni < 4; ++ni) {
    gg[ni] = g2[wn + ni * 16 + (lane & 15)];
    gb[ni] = b2g[wn + ni * 16 + (lane & 15)];
  }
#pragma unroll
  for (int mi = 0; mi < 4; ++mi) {
#pragma unroll
    for (int reg = 0; reg < 4; ++reg) {
      const int lrow = wm + mi * 16 + (lane >> 4) * 4 + reg;
      const int row = bm + lrow;
      if (row >= M) continue;
      const float mu = muA[lrow], is = isA[lrow];
#pragma unroll
      for (int ni = 0; ni < 4; ++ni) {
        const int col = wn + ni * 16 + (lane & 15);
        hn[(size_t)row * 256 + col] = f2bf((acc[mi][ni][reg] - mu) * is * gg[ni] + gb[ni]);
      }
    }
  }
}

// ---- FFN1: u = gelu(hn @ W1t^T + b1). 8 waves, BM=128, BN=256 (of 512) -----
__launch_bounds__(512, 4)
__global__ void gemm_ffn1(const ushort* __restrict__ A, const ushort* __restrict__ Bt,
                          const float* __restrict__ bias, ushort* __restrict__ u, int M) {
  __shared__ ushort As[128 * 64];
  __shared__ ushort Bs[256 * 64];
  const int tid = threadIdx.x;
  const int wave = tid >> 6, lane = tid & 63;
  const int bm = blockIdx.x * 128;
  const int bn = blockIdx.y * 256;
  const int wm = (wave >> 2) * 64, wn = (wave & 3) * 64;
  const int srow = lane >> 3;
  const int scol = (((lane & 7) ^ srow) << 3);

  f32x4 acc[4][4];
#pragma unroll
  for (int i = 0; i < 4; ++i)
#pragma unroll
    for (int j = 0; j < 4; ++j) acc[i][j] = (f32x4){0.f, 0.f, 0.f, 0.f};

  for (int k0 = 0; k0 < 256; k0 += 64) {
#pragma unroll
    for (int r = 0; r < 2; ++r) {
      const int ch = r * 8 + wave;
      int ar = bm + ch * 8 + srow;
      ar = (ar < M) ? ar : (M - 1);
      gload16(A + (size_t)ar * 256 + k0 + scol, (char*)As + ch * 1024);
    }
#pragma unroll
    for (int r = 0; r < 4; ++r) {
      const int ch = r * 8 + wave;
      const int br = bn + ch * 8 + srow;
      gload16(Bt + (size_t)br * 256 + k0 + scol, (char*)Bs + ch * 1024);
    }
    __syncthreads();
#pragma unroll
    for (int kk = 0; kk < 2; ++kk) {
      const int c = (kk * 32 + (lane >> 4) * 8) * 2;
      short8 a[4];
#pragma unroll
      for (int mi = 0; mi < 4; ++mi) {
        const int rr = wm + mi * 16 + (lane & 15);
        a[mi] = *(const short8*)((const char*)As + rr * 128 + (c ^ ((rr & 7) << 4)));
      }
#pragma unroll
      for (int ni = 0; ni < 4; ++ni) {
        const int rr = wn + ni * 16 + (lane & 15);
        short8 b = *(const short8*)((const char*)Bs + rr * 128 + (c ^ ((rr & 7) << 4)));
#pragma unroll
        for (int mi = 0; mi < 4; ++mi)
          acc[mi][ni] = __builtin_amdgcn_mfma_f32_16x16x32_bf16(a[mi], b,
                                                                acc[mi][ni], 0, 0, 0);
      }
    }
    __syncthreads();
  }

  float bb[4];
#pragma unroll
  for (int ni = 0; ni < 4; ++ni) bb[ni] = bias[bn + wn + ni * 16 + (lane & 15)];
#pragma unroll
  for (int mi = 0; mi < 4; ++mi) {
#pragma unroll
    for (int reg = 0; reg < 4; ++reg) {
      const int row = bm + wm + mi * 16 + (lane >> 4) * 4 + reg;
      if (row >= M) continue;
#pragma unroll
      for (int ni = 0; ni < 4; ++ni) {
        const int col = bn + wn + ni * 16 + (lane & 15);
        u[(size_t)row * 512 + col] = f2bf(gelu_f(acc[mi][ni][reg] + bb[ni]));
      }
    }
  }
}

// -------- fused FFN2 + residual + LN1_{l+1}: 8 waves, tile 128x256, K=512 ----
template <int LAST>
__launch_bounds__(512, 4)
__global__ void gemm_ffn2ln(const ushort* __restrict__ A, const ushort* __restrict__ Bt,
                            const float* __restrict__ bias, const float* __restrict__ g1,
                            const float* __restrict__ b1g, float* __restrict__ h,
                            ushort* __restrict__ hn, int M) {
  __shared__ ushort As[128 * 64];   // 16 KB
  __shared__ ushort Bs[256 * 64];   // 32 KB
  const int tid = threadIdx.x;
  const int wave = tid >> 6, lane = tid & 63;
  const int bm = blockIdx.x * 128;
  const int wm = (wave >> 2) * 64, wn = (wave & 3) * 64;
  const int srow = lane >> 3;
  const int scol = (((lane & 7) ^ srow) << 3);

  f32x4 acc[4][4];
#pragma unroll
  for (int i = 0; i < 4; ++i)
#pragma unroll
    for (int j = 0; j < 4; ++j) acc[i][j] = (f32x4){0.f, 0.f, 0.f, 0.f};

  for (int k0 = 0; k0 < 512; k0 += 64) {
#pragma unroll
    for (int r = 0; r < 2; ++r) {
      const int ch = r * 8 + wave;
      int ar = bm + ch * 8 + srow;
      ar = (ar < M) ? ar : (M - 1);
      gload16(A + (size_t)ar * 512 + k0 + scol, (char*)As + ch * 1024);
    }
#pragma unroll
    for (int r = 0; r < 4; ++r) {
      const int ch = r * 8 + wave;
      const int br = ch * 8 + srow;
      gload16(Bt + (size_t)br * 512 + k0 + scol, (char*)Bs + ch * 1024);
    }
    __syncthreads();
#pragma unroll
    for (int kk = 0; kk < 2; ++kk) {
      const int c = (kk * 32 + (lane >> 4) * 8) * 2;
      short8 a[4];
#pragma unroll
      for (int mi = 0; mi < 4; ++mi) {
        const int rr = wm + mi * 16 + (lane & 15);
        a[mi] = *(const short8*)((const char*)As + rr * 128 + (c ^ ((rr & 7) << 4)));
      }
#pragma unroll
      for (int ni = 0; ni < 4; ++ni) {
        const int rr = wn + ni * 16 + (lane & 15);
        short8 b = *(const short8*)((const char*)Bs + rr * 128 + (c ^ ((rr & 7) << 4)));
#pragma unroll
        for (int mi = 0; mi < 4; ++mi)
          acc[mi][ni] = __builtin_amdgcn_mfma_f32_16x16x32_bf16(a[mi], b,
                                                                acc[mi][ni], 0, 0, 0);
      }
    }
    __syncthreads();
  }

  float bb[4];
#pragma unroll
  for (int ni = 0; ni < 4; ++ni) bb[ni] = bias[wn + ni * 16 + (lane & 15)];

  float* redS = (float*)As;            // [4 n-waves][128 rows]
  float* redQ = redS + 512;
  float* muA  = redQ + 512;            // [128]
  float* isA  = muA + 128;             // [128]

#pragma unroll
  for (int mi = 0; mi < 4; ++mi) {
#pragma unroll
    for (int reg = 0; reg < 4; ++reg) {
      const int lrow = wm + mi * 16 + (lane >> 4) * 4 + reg;
      const int row = bm + lrow;
      const bool ok = (row < M);
      float pS = 0.f, pQ = 0.f;
#pragma unroll
      for (int ni = 0; ni < 4; ++ni) {
        const int col = wn + ni * 16 + (lane & 15);
        float t = acc[mi][ni][reg] + bb[ni];
        if (ok) t += h[(size_t)row * 256 + col];
        acc[mi][ni][reg] = t;
        if (LAST) {
          if (ok) hn[(size_t)row * 256 + col] = f2bf(t);
        } else {
          if (ok) h[(size_t)row * 256 + col] = t;
          pS += t;
          pQ += t * t;
        }
      }
      if (!LAST) {
#pragma unroll
        for (int off = 1; off < 16; off <<= 1) {
          pS += __shfl_xor(pS, off, 64);
          pQ += __shfl_xor(pQ, off, 64);
        }
        if ((lane & 15) == 0) {
          redS[(wave & 3) * 128 + lrow] = pS;
          redQ[(wave & 3) * 128 + lrow] = pQ;
        }
      }
    }
  }
  if (LAST) return;
  __syncthreads();
  if (tid < 128) {
    float S = redS[tid] + redS[128 + tid] + redS[256 + tid] + redS[384 + tid];
    float Q = redQ[tid] + redQ[128 + tid] + redQ[256 + tid] + redQ[384 + tid];
    float mu = S * (1.f / 256.f);
    muA[tid] = mu;
    isA[tid] = rsqrtf(Q * (1.f / 256.f) - mu * mu + 1e-5f);
  }
  __syncthreads();
  float gg[4], gb[4];
#pragma unroll
  for (int ni = 0; ni < 4; ++ni) {
    gg[ni] = g1[wn + ni * 16 + (lane & 15)];
    gb[ni] = b1g[wn + ni * 16 + (lane & 15)];
  }
#pragma unroll
  for (int mi = 0; mi < 4; ++mi) {
#pragma unroll
    for (int reg = 0; reg < 4; ++reg) {
      const int lrow = wm + mi * 16 + (lane >> 4) * 4 + reg;
      const int row = bm + lrow;
      if (row >= M) continue;
      const float mu = muA[lrow], is = isA[lrow];
#pragma unroll
      for (int ni = 0; ni < 4; ++ni) {
        const int col = wn + ni * 16 + (lane & 15);
        hn[(size_t)row * 256 + col] = f2bf((acc[mi][ni][reg] - mu) * is * gg[ni] + gb[ni]);
      }
    }
  }
}

// ---------------- bf16 MFMA output GEMM: C(f32) = A @ Bt^T + bias ------------
__launch_bounds__(256)
__global__ void gemm_out(const ushort* __restrict__ A, const ushort* __restrict__ Bt,
                         const float* __restrict__ bias, float* __restrict__ C, int M) {
  __shared__ ushort As[128 * 64];
  __shared__ ushort Bs[64 * 64];
  const int tid = threadIdx.x;
  const int wave = tid >> 6, lane = tid & 63;
  const int bm = blockIdx.x * 128;
  const int wm = wave * 32;
  const int srow = lane >> 3;
  const int scol = (((lane & 7) ^ srow) << 3);
  f32x4 acc[2][4];
#pragma unroll
  for (int i = 0; i < 2; ++i)
#pragma unroll
    for (int j = 0; j < 4; ++j) acc[i][j] = (f32x4){0.f, 0.f, 0.f, 0.f};

  for (int k0 = 0; k0 < 256; k0 += 64) {
#pragma unroll
    for (int r = 0; r < 4; ++r) {
      const int ch = r * 4 + wave;
      int ar = bm + ch * 8 + srow;
      ar = (ar < M) ? ar : (M - 1);
      gload16(A + (size_t)ar * 256 + k0 + scol, (char*)As + ch * 1024);
    }
#pragma unroll
    for (int r = 0; r < 2; ++r) {
      const int ch = r * 4 + wave;
      const int br = ch * 8 + srow;
      gload16(Bt + (size_t)br * 256 + k0 + scol, (char*)Bs + ch * 1024);
    }
    __syncthreads();
#pragma unroll
    for (int kk = 0; kk < 2; ++kk) {
      const int c = (kk * 32 + (lane >> 4) * 8) * 2;
      short8 a[2], b[4];
#pragma unroll
      for (int mi = 0; mi < 2; ++mi) {
        const int rr = wm + mi * 16 + (lane & 15);
        a[mi] = *(const short8*)((const char*)As + rr * 128 + (c ^ ((rr & 7) << 4)));
      }
#pragma unroll
      for (int ni = 0; ni < 4; ++ni) {
        const int rr = ni * 16 + (lane & 15);
        b[ni] = *(const short8*)((const char*)Bs + rr * 128 + (c ^ ((rr & 7) << 4)));
      }
#pragma unroll
      for (int mi = 0; mi < 2; ++mi)
#pragma unroll
        for (int ni = 0; ni < 4; ++ni)
          acc[mi][ni] = __builtin_amdgcn_mfma_f32_16x16x32_bf16(a[mi], b[ni],
                                                                acc[mi][ni], 0, 0, 0);
    }
    __syncthreads();
  }
  float bb[4];
#pragma unroll
  for (int ni = 0; ni < 4; ++ni) bb[ni] = bias[ni * 16 + (lane & 15)];
#pragma unroll
  for (int mi = 0; mi < 2; ++mi) {
#pragma unroll
    for (int reg = 0; reg < 4; ++reg) {
      const int row = bm + wm + mi * 16 + (lane >> 4) * 4 + reg;
      if (row >= M) continue;
#pragma unroll
      for (int ni = 0; ni < 4; ++ni) {
        const int col = ni * 16 + (lane & 15);
        C[(size_t)row * 64 + col] = acc[mi][ni][reg] + bb[ni];
      }
    }
  }
}

// ---- one-shot prep: weight transposes/converts (incl. Wi f16 split) + zero --
#define W_IN 65536
#define W_TOTAL (196608 + 393216 + 393216 + 16384)
__global__ void prep_k(const float* __restrict__ Wi, const float* __restrict__ Wc,
                       const float* __restrict__ W1, const float* __restrict__ W2,
                       const float* __restrict__ Wo, _Float16* __restrict__ WiTh,
                       _Float16* __restrict__ WiTl, ushort* __restrict__ WcT,
                       ushort* __restrict__ W1T, ushort* __restrict__ W2T,
                       ushort* __restrict__ WoT, float* __restrict__ zbase, int zn) {
  int i = blockIdx.x * 256 + threadIdx.x;
  if (i < W_IN) {
    int n = i >> 8, k = i & 255;
    float w = Wi[(size_t)k * 256 + n];
    _Float16 hv = (_Float16)w;
    WiTh[i] = hv;
    WiTl[i] = (_Float16)((w - (float)hv) * 2048.f);
  } else if ((i -= W_IN) < W_TOTAL) {
    int j = i;
    if (j < 196608) {
      int l = j / 65536, r = j % 65536, n = r >> 8, k = r & 255;
      WcT[j] = f2bf(Wc[(size_t)l * 65536 + k * 256 + n]);
    } else if ((j -= 196608) < 393216) {
      int l = j / 131072, r = j % 131072, n = r >> 8, k = r & 255;
      W1T[j] = f2bf(W1[(size_t)l * 131072 + k * 512 + n]);
    } else if ((j -= 393216) < 393216) {
      int l = j / 131072, r = j % 131072, n = r >> 9, k = r & 511;
      W2T[j] = f2bf(W2[(size_t)l * 131072 + k * 256 + n]);
    } else {
      j -= 393216;
      int n = j >> 8, k = j & 255;
      WoT[j] = f2bf(Wo[k * 64 + n]);
    }
  } else {
    int z = i - W_TOTAL;
    if (z < zn) zbase[z] = 0.f;
  }
}

__global__ void neigh_k(const int* __restrict__ src, const int* __restrict__ dst,
                        const float* __restrict__ delta, float* __restrict__ neigh, int E) {
  int e = blockIdx.x * 256 + threadIdx.x;
  if (e < E) atomicAdd(&neigh[dst[e]], delta[src[e]]);
}

// edge logits (pi inline); slots layout [t][N]
__global__ void logits_k(const int* __restrict__ src, const int* __restrict__ dst,
                         const float* __restrict__ adst, const float* __restrict__ asrc,
                         const float* __restrict__ xwp, const float* __restrict__ neigh,
                         const float* __restrict__ Wa, const float* __restrict__ ba,
                         float* __restrict__ expe, float* __restrict__ denom,
                         int* __restrict__ cnt, int* __restrict__ slots,
                         int E, int Et, int N) {
  int e = blockIdx.x * 256 + threadIdx.x;
  if (e >= Et) return;
  int s, d;
  if (e < E) { s = src[e]; d = dst[e]; } else { s = e - E; d = s; }
  float pis = 1.f / (1.f + expf(-(xwp[s] + neigh[s])));
  float v = adst[d] + asrc[s] + pis * Wa[512] + ba[0];
  v = (v >= 0.f ? v : 0.2f * v) / TAUF;
  v = fminf(fmaxf(v, -5.f), 5.f);
  float ex = expf(v);
  expe[e] = ex;
  atomicAdd(&denom[d], ex);
  int p = atomicAdd(&cnt[d], 1);
  if (p < 64) slots[(size_t)p * N + d] = e;
}

__device__ __forceinline__ bool better(float a, int e, float a2, int e2) {
  return a > a2 || (a == a2 && e < e2);
}

// top-8 + renormalize; ksrc/kw padded to exactly 8 entries (w=0)
__global__ void topk_k(const int* __restrict__ cnt, const int* __restrict__ slots,
                       const float* __restrict__ expe, const float* __restrict__ denom,
                       const int* __restrict__ src, int* __restrict__ ksrc,
                       float* __restrict__ kw, int N, int E) {
  int d = blockIdx.x * 256 + threadIdx.x;
  if (d >= N) return;
  int deg = min(cnt[d], 64);
  float D = denom[d] + 1e-16f;
  float av[8]; int ai[8]; int kc = 0;
  for (int t = 0; t < deg; ++t) {
    int e = slots[(size_t)t * N + d];
    float a = expe[e] / D;
    if (kc < 8) {
      int p = kc++;
      while (p > 0 && better(a, e, av[p - 1], ai[p - 1])) {
        av[p] = av[p - 1]; ai[p] = ai[p - 1]; --p;
      }
      av[p] = a; ai[p] = e;
    } else if (better(a, e, av[7], ai[7])) {
      int p = 7;
      while (p > 0 && better(a, e, av[p - 1], ai[p - 1])) {
        av[p] = av[p - 1]; ai[p] = ai[p - 1]; --p;
      }
      av[p] = a; ai[p] = e;
    }
  }
  float ks = 0.f;
  for (int j = 0; j < kc; ++j) ks += av[j];
  float inv = 1.f / (ks + 1e-16f);
#pragma unroll
  for (int j = 0; j < 8; ++j) {
    if (j < kc) {
      int e = ai[j];
      ksrc[(size_t)d * 8 + j] = (e < E) ? src[e] : (e - E);
      kw[(size_t)d * 8 + j] = av[j] * inv;
    } else {
      ksrc[(size_t)d * 8 + j] = 0;
      kw[(size_t)d * 8 + j] = 0.f;
    }
  }
}

extern "C" void kernel_launch(void* const* d_in, const int* in_sizes, int n_in,
                              void* d_out, int out_size, void* d_ws, size_t ws_size,
                              hipStream_t stream) {
  const float* X   = (const float*)d_in[0];
  const int*   EI  = (const int*)d_in[1];
  const float* Wi  = (const float*)d_in[2];
  const float* bi  = (const float*)d_in[3];
  const float* wp  = (const float*)d_in[4];
  const float* Wa  = (const float*)d_in[5];
  const float* ba  = (const float*)d_in[6];
  const float* l1g = (const float*)d_in[7];
  const float* l1b = (const float*)d_in[8];
  const float* l2g = (const float*)d_in[9];
  const float* l2b = (const float*)d_in[10];
  const float* W1  = (const float*)d_in[11];
  const float* b1  = (const float*)d_in[12];
  const float* W2  = (const float*)d_in[13];
  const float* b2  = (const float*)d_in[14];
  const float* Wc  = (const float*)d_in[15];
  const float* bc  = (const float*)d_in[16];
  const float* Wo  = (const float*)d_in[17];
  const float* bo  = (const float*)d_in[18];

  const int N = in_sizes[0] / 256;
  const int E = in_sizes[1] / 2;
  const int Et = E + N;
  const int* srcp = EI;
  const int* dstp = EI + E;

  float* ws = (float*)d_ws;
  size_t off = 0;
  auto alloc = [&](size_t n) { float* p = ws + off; off += n; return p; };
  const size_t NH = (size_t)N * 256;
  float*  h    = alloc(NH);                            // f32 [N][256]
  ushort* hn   = (ushort*)alloc(NH / 2);               // bf16 [N][256]
  ushort* hagg = (ushort*)alloc(NH / 2);               // bf16 [N][256]
  float*  ualias = alloc(NH);                          // u (bf16 [N][512]) / Xh+Xl
  ushort* u    = (ushort*)ualias;
  _Float16* Xh = (_Float16*)ualias;
  _Float16* Xl = Xh + NH;
  _Float16* WiTh = (_Float16*)alloc(65536 / 2);
  _Float16* WiTl = (_Float16*)alloc(65536 / 2);
  ushort* WcT  = (ushort*)alloc(3 * 65536 / 2);
  ushort* W1T  = (ushort*)alloc(3 * 131072 / 2);
  ushort* W2T  = (ushort*)alloc(3 * 131072 / 2);
  ushort* WoT  = (ushort*)alloc(16384 / 2);
  float* delta = alloc(N);
  float* adst  = alloc(N);
  float* asrc  = alloc(N);
  float* xwp   = alloc(N);
  float* expe  = alloc(Et);
  float* neigh = alloc(N);       // ┐ contiguous zero region (3N)
  float* denom = alloc(N);       // │
  int*   cnt   = (int*)alloc(N); // ┘
  int*   slots = (int*)alloc((size_t)N * 64);
  int*   ksrc  = (int*)alloc((size_t)N * 8);
  float* kw    = alloc((size_t)N * 8);

  prep_k<<<(W_IN + W_TOTAL + 3 * N + 255) / 256, 256, 0, stream>>>(
      Wi, Wc, W1, W2, Wo, WiTh, WiTl, WcT, W1T, W2T, WoT, neigh, 3 * N);
  xsplit_k<<<((int)(NH / 4) + 255) / 256, 256, 0, stream>>>(X, Xh, Xl, (int)(NH / 4));

  gemm_in_mfma<<<(N + 63) / 64, 256, 0, stream>>>(
      Xh, Xl, WiTh, WiTl, bi, Wa, wp, l1g, l1b, h, hn,
      delta, adst, asrc, xwp, N);
  neigh_k<<<(E + 255) / 256, 256, 0, stream>>>(srcp, dstp, delta, neigh, E);
  logits_k<<<(Et + 255) / 256, 256, 0, stream>>>(srcp, dstp, adst, asrc, xwp, neigh,
                                                 Wa, ba, expe, denom, cnt, slots,
                                                 E, Et, N);
  topk_k<<<(N + 255) / 256, 256, 0, stream>>>(cnt, slots, expe, denom, srcp,
                                              ksrc, kw, N, E);

  const int GM = (N + 127) / 128;
  for (int l = 0; l < 3; ++l) {
    gather_k<<<(N + 3) / 4, 256, 0, stream>>>(hn, ksrc, kw, hagg, N);
    gemm_conv_aggln<<<GM, 512, 0, stream>>>(
        hagg, WcT + (size_t)l * 65536, bc + l * 256,
        l2g + l * 256, l2b + l * 256, h, hn, N);
    gemm_ffn1<<<dim3(GM, 2), 512, 0, stream>>>(
        hn, W1T + (size_t)l * 131072, b1 + l * 512, u, N);
    if (l < 2)
      gemm_ffn2ln<0><<<GM, 512, 0, stream>>>(
          u, W2T + (size_t)l * 131072, b2 + l * 256,
          l1g + (l + 1) * 256, l1b + (l + 1) * 256, h, hn, N);
    else
      gemm_ffn2ln<1><<<GM, 512, 0, stream>>>(
          u, W2T + (size_t)l * 131072, b2 + l * 256,
          nullptr, nullptr, h, hn, N);
  }
  gemm_out<<<(N + 127) / 128, 256, 0, stream>>>(hn, WoT, bo, (float*)d_out, N);
}